// Round 18
// baseline (510.933 us; speedup 1.0000x reference)
//
#include <hip/hip_runtime.h>
#include <hip/hip_bf16.h>
#include <stdint.h>

#define BB 4
#define NN 16384
#define HDIM 1024
#define HH 8
#define MM 32
#define DD 128

typedef unsigned int u32;
typedef unsigned short u16;
typedef __attribute__((ext_vector_type(8))) short short8;
typedef __attribute__((ext_vector_type(4))) float f32x4;

__device__ __forceinline__ float bf2f(u16 v) {
    union { u32 u; float f; } c; c.u = ((u32)v) << 16; return c.f;
}
__device__ __forceinline__ u16 f2bf(float f) {
    union { float f; u32 u; } c; c.f = f;
    u32 r = c.u + 0x7fffu + ((c.u >> 16) & 1u);
    return (u16)(r >> 16);
}

__device__ __forceinline__ void gload16(const u16* g, u16* l) {
    __builtin_amdgcn_global_load_lds(
        (const __attribute__((address_space(1))) void*)g,
        (__attribute__((address_space(3))) void*)l, 16, 0, 0);
}

#define MFMA16(a, b, c) __builtin_amdgcn_mfma_f32_16x16x32_bf16(a, b, c, 0, 0, 0)

// ---------------------------------------------------------------- convert + transpose
__global__ __launch_bounds__(256) void convert_kernel(const float* __restrict__ x,
                                                      u16* __restrict__ xb, u16* __restrict__ xbT,
                                                      const float* __restrict__ wtq_bias,
                                                      float* __restrict__ out_misc) {
    __shared__ u32 tl[128 * 65];
    const int t = threadIdx.x;
    const int eb = blockIdx.x & 7;
    const int nb = blockIdx.x >> 3;
    const size_t n0 = (size_t)nb * 128;
    const int e0 = eb * 128;

#pragma unroll 4
    for (int i = 0; i < 32; i++) {
        const int idx = t + i * 256;
        const int nl = idx >> 6, e2 = idx & 63;
        const float2 v = *(const float2*)&x[(n0 + nl) * 1024 + e0 + e2 * 2];
        const u32 pk = (u32)f2bf(v.x) | ((u32)f2bf(v.y) << 16);
        ((u32*)xb)[((n0 + nl) * 1024 + e0) / 2 + e2] = pk;
        tl[nl * 65 + e2] = pk;
    }
    __syncthreads();
    const int b = (int)(n0 >> 14);
    const int nloc = (int)(n0 & 16383);
#pragma unroll 4
    for (int i = 0; i < 32; i++) {
        const int idx = t + i * 256;
        const int el = idx >> 6, n2 = idx & 63;
        const u32 w0 = tl[(2 * n2) * 65 + (el >> 1)];
        const u32 w1 = tl[(2 * n2 + 1) * 65 + (el >> 1)];
        const int sh = (el & 1) * 16;
        const u32 o = ((w0 >> sh) & 0xffffu) | (((w1 >> sh) & 0xffffu) << 16);
        ((u32*)xbT)[((size_t)(b * 1024 + e0 + el) * 16384 + nloc + 2 * n2) >> 1] = o;
    }
    if (blockIdx.x == 0) {
        if (t == 0) out_misc[0] = 1.0f;
        if (t < HH * MM) out_misc[1 + t] = wtq_bias[t];
    }
}

// ---------------------------------------------------------------- WQ = wtq @ Wkv_K ; wq_bias; Wv -> bf16
__global__ __launch_bounds__(256) void wq_kernel(const float* __restrict__ wtq,
                                                 const float* __restrict__ wkv,
                                                 const float* __restrict__ bkv,
                                                 u16* __restrict__ WQb, float* __restrict__ wqbias,
                                                 u16* __restrict__ wvb) {
    __shared__ float wtql[MM * DD];
    const int ec = blockIdx.x, h = blockIdx.y, t = threadIdx.x;
    for (int i = t; i < MM * DD; i += 256) wtql[i] = wtq[(size_t)h * MM * DD + i];
    __syncthreads();
    const int m = t >> 3;
    const int e = ec * 128 + (t & 7) * 16;
    float acc[16];
#pragma unroll
    for (int j = 0; j < 16; j++) acc[j] = 0.f;
    for (int d = 0; d < DD; d++) {
        const float wv = wtql[m * DD + d];
        const float4* row = (const float4*)(wkv + (size_t)(h * DD + d) * HDIM + e);
#pragma unroll
        for (int j4 = 0; j4 < 4; j4++) {
            float4 v = row[j4];
            acc[j4 * 4 + 0] += wv * v.x; acc[j4 * 4 + 1] += wv * v.y;
            acc[j4 * 4 + 2] += wv * v.z; acc[j4 * 4 + 3] += wv * v.w;
        }
    }
    u32 pk[8];
#pragma unroll
    for (int p = 0; p < 8; p++)
        pk[p] = (u32)f2bf(acc[2 * p]) | ((u32)f2bf(acc[2 * p + 1]) << 16);
    u16* dst = WQb + (size_t)(h * MM + m) * HDIM + e;
#pragma unroll
    for (int p = 0; p < 2; p++) {
        uint4 q4; q4.x = pk[4 * p]; q4.y = pk[4 * p + 1]; q4.z = pk[4 * p + 2]; q4.w = pk[4 * p + 3];
        *(uint4*)&dst[p * 8] = q4;
    }
    if (ec == 0 && t < MM) {
        float s = 0.f;
        for (int d = 0; d < DD; d++) s += wtql[t * DD + d] * bkv[h * DD + d];
        wqbias[h * MM + t] = s;
    }
    {
        const int blk = blockIdx.y * 8 + blockIdx.x;
        const float4* src = (const float4*)(wkv + (size_t)1024 * 1024);
        for (int i = t; i < 4096; i += 256) {
            const int idx4 = blk * 4096 + i;
            float4 v = src[idx4];
            ushort4 o; o.x = f2bf(v.x); o.y = f2bf(v.y); o.z = f2bf(v.z); o.w = f2bf(v.w);
            ((ushort4*)wvb)[idx4] = o;
        }
    }
}

// ---------------------------------------------------------------- fused scores GEMM + softmax
__global__ __launch_bounds__(512, 1) void gemm_score_sm(
        const u16* __restrict__ A, const u16* __restrict__ Bm,
        const float* __restrict__ bias,
        float* __restrict__ sw_out, u16* __restrict__ wN, u16* __restrict__ wT,
        float* __restrict__ pnorm) {
    __shared__ u16 smem[65536];
    const int t = threadIdx.x, l = t & 63, w = t >> 6;
    const int wr = w >> 2, wc = w & 3;

    const int nwg = gridDim.x, cpx = nwg >> 3, bid = blockIdx.x;
    const int tm = (bid & 7) * cpx + (bid >> 3);   // ntn = 1

    f32x4 acc[8][4];
    const f32x4 zero = {0.f, 0.f, 0.f, 0.f};
#pragma unroll
    for (int mi = 0; mi < 8; mi++)
#pragma unroll
        for (int ni = 0; ni < 4; ni++) acc[mi][ni] = zero;

    const int srow = w * 8 + (l >> 3);
    const int skel = ((l & 7) ^ ((l >> 3) & 7)) * 8;
    const u16* gA = A  + (size_t)(tm * 256 + srow) * 1024 + skel;
    const u16* gB = Bm + (size_t)srow * 1024 + skel;
    const int ldo = w * 512 + l * 8;

#define LAp(SL, H) (&smem[(SL) * 16384 + (H) * 8192])
#define LBp(SL, H) (&smem[32768 + (SL) * 16384 + (H) * 8192])
#define STAGE_A(T, H) { const u16* g_ = gA + (size_t)((H) * 128) * 1024 + (T) * 64; \
    u16* d_ = LAp((T) & 1, H) + ldo; gload16(g_, d_); gload16(g_ + (size_t)64 * 1024, d_ + 4096); }
#define STAGE_B(T, H) { const u16* g_ = gB + (size_t)((H) * 128) * 1024 + (T) * 64; \
    u16* d_ = LBp((T) & 1, H) + ldo; gload16(g_, d_); gload16(g_ + (size_t)64 * 1024, d_ + 4096); }

    const int m16 = l & 15;
    const int ck0 = (((l >> 4) + 0) ^ (l & 7)) << 3;
    const int ck1 = (((l >> 4) + 4) ^ (l & 7)) << 3;
    const int brb = (wc & 1) * 64;
    const int nT = 16;

    STAGE_A(0, 0); STAGE_A(0, 1); STAGE_B(0, 0); STAGE_B(0, 1);
    STAGE_B(1, 0); STAGE_B(1, 1);
    asm volatile("s_waitcnt vmcnt(4)" ::: "memory");
    __builtin_amdgcn_s_barrier();

    for (int kt = 0; kt < nT; ++kt) {
        const int sl = kt & 1;
        const u16* lA = LAp(sl, wr);
        const u16* lB = LBp(sl, wc >> 1);
        short8 aF[4][2], bF[4][2];

#pragma unroll
        for (int fr = 0; fr < 4; fr++) {
            aF[fr][0] = *(const short8*)&lA[(fr * 16 + m16) * 64 + ck0];
            aF[fr][1] = *(const short8*)&lA[(fr * 16 + m16) * 64 + ck1];
        }
#pragma unroll
        for (int fc = 0; fc < 2; fc++) {
            bF[fc][0] = *(const short8*)&lB[(brb + fc * 16 + m16) * 64 + ck0];
            bF[fc][1] = *(const short8*)&lB[(brb + fc * 16 + m16) * 64 + ck1];
        }
        if (kt + 1 < nT) STAGE_A(kt + 1, 0);
        __builtin_amdgcn_s_barrier();
        asm volatile("s_waitcnt lgkmcnt(0)" ::: "memory");
        __builtin_amdgcn_s_setprio(1);
#pragma unroll
        for (int kk = 0; kk < 2; kk++)
#pragma unroll
            for (int mi = 0; mi < 4; mi++) {
                acc[mi][0] = MFMA16(aF[mi][kk], bF[0][kk], acc[mi][0]);
                acc[mi][1] = MFMA16(aF[mi][kk], bF[1][kk], acc[mi][1]);
            }
        __builtin_amdgcn_s_setprio(0);
        __builtin_amdgcn_s_barrier();

#pragma unroll
        for (int fc = 2; fc < 4; fc++) {
            bF[fc][0] = *(const short8*)&lB[(brb + fc * 16 + m16) * 64 + ck0];
            bF[fc][1] = *(const short8*)&lB[(brb + fc * 16 + m16) * 64 + ck1];
        }
        if (kt + 1 < nT) STAGE_A(kt + 1, 1);
        __builtin_amdgcn_s_barrier();
        asm volatile("s_waitcnt lgkmcnt(0)" ::: "memory");
        __builtin_amdgcn_s_setprio(1);
#pragma unroll
        for (int kk = 0; kk < 2; kk++)
#pragma unroll
            for (int mi = 0; mi < 4; mi++) {
                acc[mi][2] = MFMA16(aF[mi][kk], bF[2][kk], acc[mi][2]);
                acc[mi][3] = MFMA16(aF[mi][kk], bF[3][kk], acc[mi][3]);
            }
        __builtin_amdgcn_s_setprio(0);
        __builtin_amdgcn_s_barrier();

#pragma unroll
        for (int fr = 0; fr < 4; fr++) {
            aF[fr][0] = *(const short8*)&lA[((fr + 4) * 16 + m16) * 64 + ck0];
            aF[fr][1] = *(const short8*)&lA[((fr + 4) * 16 + m16) * 64 + ck1];
        }
        if (kt + 2 < nT) STAGE_B(kt + 2, 0);
        __builtin_amdgcn_s_barrier();
        asm volatile("s_waitcnt lgkmcnt(0)" ::: "memory");
        __builtin_amdgcn_s_setprio(1);
#pragma unroll
        for (int kk = 0; kk < 2; kk++)
#pragma unroll
            for (int mi = 0; mi < 4; mi++) {
                acc[4 + mi][0] = MFMA16(aF[mi][kk], bF[0][kk], acc[4 + mi][0]);
                acc[4 + mi][1] = MFMA16(aF[mi][kk], bF[1][kk], acc[4 + mi][1]);
            }
        __builtin_amdgcn_s_setprio(0);
        __builtin_amdgcn_s_barrier();

        if (kt + 2 < nT) STAGE_B(kt + 2, 1);
        __builtin_amdgcn_s_barrier();
        __builtin_amdgcn_s_setprio(1);
#pragma unroll
        for (int kk = 0; kk < 2; kk++)
#pragma unroll
            for (int mi = 0; mi < 4; mi++) {
                acc[4 + mi][2] = MFMA16(aF[mi][kk], bF[2][kk], acc[4 + mi][2]);
                acc[4 + mi][3] = MFMA16(aF[mi][kk], bF[3][kk], acc[4 + mi][3]);
            }
        __builtin_amdgcn_s_setprio(0);
        if (kt < nT - 1) {
            if (kt + 2 < nT) asm volatile("s_waitcnt vmcnt(4)" ::: "memory");
            else             asm volatile("s_waitcnt vmcnt(0)" ::: "memory");
            __builtin_amdgcn_s_barrier();
        }
    }
#undef STAGE_A
#undef STAGE_B
#undef LAp
#undef LBp

    // ---- epilogue: scores -> LDS sc[hm][n] (bf16, +bias), 8B-chunk XOR swizzle
    __syncthreads();
    const int cr = (l >> 4) * 4;
    const int cc = l & 15;
#pragma unroll
    for (int ni = 0; ni < 4; ni++) {
        const int hm = wc * 64 + ni * 16 + cc;
        const float bv = bias[hm];
#pragma unroll
        for (int mi = 0; mi < 8; mi++) {
            const int nb_ = wr * 128 + mi * 16 + cr;
            u32 lo = (u32)f2bf(acc[mi][ni][0] + bv) | ((u32)f2bf(acc[mi][ni][1] + bv) << 16);
            u32 hi = (u32)f2bf(acc[mi][ni][2] + bv) | ((u32)f2bf(acc[mi][ni][3] + bv) << 16);
            uint2 pk; pk.x = lo; pk.y = hi;
            *(uint2*)&smem[hm * 256 + (((nb_ >> 2) ^ (hm & 63)) << 2)] = pk;
        }
    }
    __syncthreads();

    // ---- softmax over m: thread t -> n = t&255, h in [hs, hs+4)
    const int b = tm >> 6, g = tm & 63;
    const int n_ = t & 255, hs = (t >> 8) * 4;
    const size_t gn = (size_t)g * 256 + n_;
    for (int h = hs; h < hs + 4; h++) {
        float sv[MM];
#pragma unroll
        for (int m = 0; m < MM; m++) {
            const int hm = h * 32 + m;
            sv[m] = bf2f(smem[hm * 256 + (((n_ >> 2) ^ (hm & 63)) << 2) + (n_ & 3)]);
        }
        float mx = sv[0];
#pragma unroll
        for (int m = 1; m < MM; m++) mx = fmaxf(mx, sv[m]);
        float sum = 0.f;
#pragma unroll
        for (int m = 0; m < MM; m++) { sv[m] = __expf(sv[m] - mx); sum += sv[m]; }
        const float inv = 1.f / sum;
        u32 wpk[16];
#pragma unroll
        for (int m = 0; m < MM; m++) {
            const float wv = sv[m] * inv;
            const int hm = h * 32 + m;
            const size_t row = (size_t)(b * 256 + hm);
            sw_out[row * NN + gn] = wv;
            const u16 wb = f2bf(wv);
            wN[row * NN + gn] = wb;
            smem[hm * 256 + (((n_ >> 2) ^ (hm & 63)) << 2) + (n_ & 3)] = wb;
            if (m & 1) wpk[m >> 1] |= ((u32)wb << 16); else wpk[m >> 1] = (u32)wb;
        }
        u16* wrow = wT + ((size_t)(b * NN) + gn) * 256 + h * 32;
#pragma unroll
        for (int p = 0; p < 4; p++) {
            uint4 q4; q4.x = wpk[4 * p]; q4.y = wpk[4 * p + 1]; q4.z = wpk[4 * p + 2]; q4.w = wpk[4 * p + 3];
            *(uint4*)&wrow[p * 8] = q4;
        }
    }
    __syncthreads();

    // ---- pnorm: thread t -> hm = t>>1, half = t&1 (128 n each)
    {
        const int hm2 = t >> 1, half = t & 1;
        float s = 0.f;
        for (int j = 0; j < 128; j++) {
            const int n2 = half * 128 + j;
            s += bf2f(smem[hm2 * 256 + (((n2 >> 2) ^ (hm2 & 63)) << 2) + (n2 & 3)]);
        }
        s += __shfl_xor(s, 1);
        if (half == 0)
            pnorm[((size_t)(b * 8 + (hm2 >> 5)) * 64 + g) * MM + (hm2 & 31)] = s;
    }
}

// ---------------------------------------------------------------- unified 8-phase GEMM (256x256), MODE 2 bf16 C
template<int MODE>
__global__ __launch_bounds__(512, 1) void gemm_nt(
        const u16* __restrict__ A, const u16* __restrict__ Bm,
        const float* __restrict__ bias, void* __restrict__ Cout,
        int NCols, int Kd, int ldk, int ntn, int bofs, int bshift,
        long long bstrideB, long long kCstride) {
    __shared__ u16 ldsA[2][2][8192];
    __shared__ u16 ldsB[2][2][8192];
    const int t = threadIdx.x, l = t & 63, w = t >> 6;
    const int wr = w >> 2, wc = w & 3;

    const int nwg = gridDim.x, cpx = nwg >> 3, bid = blockIdx.x;
    const int swz = (nwg >= 8) ? ((bid & 7) * cpx + (bid >> 3)) : bid;
    const int tm = swz / ntn, tn = swz % ntn;
    const int ks = blockIdx.y;
    const u16* Bb = Bm + (size_t)(tm >> bshift) * bstrideB;

    f32x4 acc[8][4];
    const f32x4 zero = {0.f, 0.f, 0.f, 0.f};
#pragma unroll
    for (int mi = 0; mi < 8; mi++)
#pragma unroll
        for (int ni = 0; ni < 4; ni++) acc[mi][ni] = zero;

    const int srow = w * 8 + (l >> 3);
    const int skel = ((l & 7) ^ ((l >> 3) & 7)) * 8;
    const u16* gA = A  + (size_t)(tm * 256 + srow) * ldk + (size_t)ks * Kd + skel;
    const u16* gB = Bb + (size_t)(tn * 256 + srow) * ldk + (size_t)ks * Kd + skel;
    const int ldo = w * 512 + l * 8;

#define STAGE_A(T, H) { const u16* g_ = gA + (size_t)((H) * 128) * ldk + (T) * 64; \
    u16* d_ = &ldsA[(T) & 1][H][ldo]; gload16(g_, d_); gload16(g_ + (size_t)64 * ldk, d_ + 4096); }
#define STAGE_B(T, H) { const u16* g_ = gB + (size_t)((H) * 128) * ldk + (T) * 64; \
    u16* d_ = &ldsB[(T) & 1][H][ldo]; gload16(g_, d_); gload16(g_ + (size_t)64 * ldk, d_ + 4096); }

    const int m16 = l & 15;
    const int ck0 = (((l >> 4) + 0) ^ (l & 7)) << 3;
    const int ck1 = (((l >> 4) + 4) ^ (l & 7)) << 3;
    const int brb = (wc & 1) * 64;
    const int nT = Kd >> 6;

    STAGE_A(0, 0); STAGE_A(0, 1); STAGE_B(0, 0); STAGE_B(0, 1);
    STAGE_B(1, 0); STAGE_B(1, 1);
    asm volatile("s_waitcnt vmcnt(4)" ::: "memory");
    __builtin_amdgcn_s_barrier();

    for (int kt = 0; kt < nT; ++kt) {
        const int sl = kt & 1;
        const u16* lA = ldsA[sl][wr];
        const u16* lB = ldsB[sl][wc >> 1];
        short8 aF[4][2], bF[4][2];

#pragma unroll
        for (int fr = 0; fr < 4; fr++) {
            aF[fr][0] = *(const short8*)&lA[(fr * 16 + m16) * 64 + ck0];
            aF[fr][1] = *(const short8*)&lA[(fr * 16 + m16) * 64 + ck1];
        }
#pragma unroll
        for (int fc = 0; fc < 2; fc++) {
            bF[fc][0] = *(const short8*)&lB[(brb + fc * 16 + m16) * 64 + ck0];
            bF[fc][1] = *(const short8*)&lB[(brb + fc * 16 + m16) * 64 + ck1];
        }
        if (kt + 1 < nT) STAGE_A(kt + 1, 0);
        __builtin_amdgcn_s_barrier();
        asm volatile("s_waitcnt lgkmcnt(0)" ::: "memory");
        __builtin_amdgcn_s_setprio(1);
#pragma unroll
        for (int kk = 0; kk < 2; kk++)
#pragma unroll
            for (int mi = 0; mi < 4; mi++) {
                acc[mi][0] = MFMA16(aF[mi][kk], bF[0][kk], acc[mi][0]);
                acc[mi][1] = MFMA16(aF[mi][kk], bF[1][kk], acc[mi][1]);
            }
        __builtin_amdgcn_s_setprio(0);
        __builtin_amdgcn_s_barrier();

#pragma unroll
        for (int fc = 2; fc < 4; fc++) {
            bF[fc][0] = *(const short8*)&lB[(brb + fc * 16 + m16) * 64 + ck0];
            bF[fc][1] = *(const short8*)&lB[(brb + fc * 16 + m16) * 64 + ck1];
        }
        if (kt + 1 < nT) STAGE_A(kt + 1, 1);
        __builtin_amdgcn_s_barrier();
        asm volatile("s_waitcnt lgkmcnt(0)" ::: "memory");
        __builtin_amdgcn_s_setprio(1);
#pragma unroll
        for (int kk = 0; kk < 2; kk++)
#pragma unroll
            for (int mi = 0; mi < 4; mi++) {
                acc[mi][2] = MFMA16(aF[mi][kk], bF[2][kk], acc[mi][2]);
                acc[mi][3] = MFMA16(aF[mi][kk], bF[3][kk], acc[mi][3]);
            }
        __builtin_amdgcn_s_setprio(0);
        __builtin_amdgcn_s_barrier();

#pragma unroll
        for (int fr = 0; fr < 4; fr++) {
            aF[fr][0] = *(const short8*)&lA[((fr + 4) * 16 + m16) * 64 + ck0];
            aF[fr][1] = *(const short8*)&lA[((fr + 4) * 16 + m16) * 64 + ck1];
        }
        if (kt + 2 < nT) STAGE_B(kt + 2, 0);
        __builtin_amdgcn_s_barrier();
        asm volatile("s_waitcnt lgkmcnt(0)" ::: "memory");
        __builtin_amdgcn_s_setprio(1);
#pragma unroll
        for (int kk = 0; kk < 2; kk++)
#pragma unroll
            for (int mi = 0; mi < 4; mi++) {
                acc[4 + mi][0] = MFMA16(aF[mi][kk], bF[0][kk], acc[4 + mi][0]);
                acc[4 + mi][1] = MFMA16(aF[mi][kk], bF[1][kk], acc[4 + mi][1]);
            }
        __builtin_amdgcn_s_setprio(0);
        __builtin_amdgcn_s_barrier();

        if (kt + 2 < nT) STAGE_B(kt + 2, 1);
        __builtin_amdgcn_s_barrier();
        __builtin_amdgcn_s_setprio(1);
#pragma unroll
        for (int kk = 0; kk < 2; kk++)
#pragma unroll
            for (int mi = 0; mi < 4; mi++) {
                acc[4 + mi][2] = MFMA16(aF[mi][kk], bF[2][kk], acc[4 + mi][2]);
                acc[4 + mi][3] = MFMA16(aF[mi][kk], bF[3][kk], acc[4 + mi][3]);
            }
        __builtin_amdgcn_s_setprio(0);
        if (kt < nT - 1) {
            if (kt + 2 < nT) asm volatile("s_waitcnt vmcnt(4)" ::: "memory");
            else             asm volatile("s_waitcnt vmcnt(0)" ::: "memory");
            __builtin_amdgcn_s_barrier();
        }
    }
#undef STAGE_A
#undef STAGE_B

    const int cr = (l >> 4) * 4;
    const int cc = l & 15;
    if (MODE == 2) {
        u16* Cp = (u16*)Cout + (size_t)ks * kCstride;
#pragma unroll
        for (int ni = 0; ni < 4; ni++) {
            const int col = tn * 256 + wc * 64 + ni * 16 + cc;
            const float bv = bias ? bias[col] : 0.0f;
#pragma unroll
            for (int mi = 0; mi < 8; mi++) {
                const int row0 = tm * 256 + wr * 128 + mi * 16 + cr;
#pragma unroll
                for (int q = 0; q < 4; q++)
                    Cp[(size_t)(row0 + q) * NCols + col] = f2bf(acc[mi][ni][q] + bv);
            }
        }
    } else {
        float* Cp = (float*)Cout + (size_t)ks * kCstride;
#pragma unroll
        for (int ni = 0; ni < 4; ni++) {
            const int col = tn * 256 + wc * 64 + ni * 16 + cc;
            const float bv = bias ? bias[col] : 0.0f;
#pragma unroll
            for (int mi = 0; mi < 8; mi++) {
                const int row0 = tm * 256 + wr * 128 + mi * 16 + cr;
#pragma unroll
                for (int q = 0; q < 4; q++)
                    Cp[(size_t)(row0 + q) * NCols + col] = acc[mi][ni][q] + bv;
            }
        }
    }
}

// ---------------------------------------------------------------- small 2-phase GEMM (128x128, BK=32, 16 KB LDS)
__global__ __launch_bounds__(256, 2) void gemm_small(
        const u16* __restrict__ A, const u16* __restrict__ Bm,
        const float* __restrict__ bias, float* __restrict__ Cout,
        int Ncols, int Kds, int ldk, int ntn, int bshift,
        long long bstrideB, long long kCstride) {
    __shared__ u16 lds_a[128 * 32];
    __shared__ u16 lds_b[128 * 32];
    const int t = threadIdx.x, l = t & 63, w = t >> 6;
    const int wr = w >> 1, wc = w & 1;

    const int nwg = gridDim.x, cpx = nwg >> 3, bid = blockIdx.x;
    const int swz = (nwg >= 8) ? ((bid & 7) * cpx + (bid >> 3)) : bid;
    const int tm = swz / ntn, tn = swz % ntn;
    const int ks = blockIdx.y;
    const u16* Bb = Bm + (size_t)(tm >> bshift) * bstrideB;

    f32x4 acc[4][4];
    const f32x4 zero = {0.f, 0.f, 0.f, 0.f};
#pragma unroll
    for (int mi = 0; mi < 4; mi++)
#pragma unroll
        for (int ni = 0; ni < 4; ni++) acc[mi][ni] = zero;

    const int srow = w * 32 + (l >> 2);
    const int scol = (l & 3) * 8;
    const u16* ga = A  + (size_t)(tm * 128 + srow) * ldk + (size_t)ks * Kds + scol;
    const u16* gb = Bb + (size_t)(tn * 128 + srow) * ldk + (size_t)ks * Kds + scol;
    u16* la = &lds_a[(w * 32) * 32];
    u16* lb = &lds_b[(w * 32) * 32];
    const size_t rstep = (size_t)16 * ldk;

    const int nK = Kds >> 5;
    const int kg = (l >> 4) * 8;
    const int ra = wr * 64 + (l & 15);
    const int rb = wc * 64 + (l & 15);

    for (int kt = 0; kt < nK; kt++) {
        __syncthreads();
        const int ko = kt << 5;
        gload16(ga + ko,         la);
        gload16(ga + ko + rstep, la + 16 * 32);
        gload16(gb + ko,         lb);
        gload16(gb + ko + rstep, lb + 16 * 32);
        __syncthreads();

        short8 af[4], bfr[4];
#pragma unroll
        for (int mi = 0; mi < 4; mi++) af[mi] = *(const short8*)&lds_a[(ra + mi * 16) * 32 + kg];
#pragma unroll
        for (int ni = 0; ni < 4; ni++) bfr[ni] = *(const short8*)&lds_b[(rb + ni * 16) * 32 + kg];
#pragma unroll
        for (int mi = 0; mi < 4; mi++)
#pragma unroll
            for (int ni = 0; ni < 4; ni++)
                acc[mi][ni] = MFMA16(af[mi], bfr[ni], acc[mi][ni]);
    }

    float* Cp = Cout + (size_t)ks * kCstride;
#pragma unroll
    for (int ni = 0; ni < 4; ni++) {
        const int col = tn * 128 + wc * 64 + ni * 16 + (l & 15);
        const float bv = bias ? bias[col] : 0.0f;
#pragma unroll
        for (int mi = 0; mi < 4; mi++) {
            const int row0 = tm * 128 + wr * 64 + mi * 16 + ((l >> 4) << 2);
#pragma unroll
            for (int q = 0; q < 4; q++)
                Cp[(size_t)(row0 + q) * Ncols + col] = acc[mi][ni][q] + bv;
        }
    }
}

// ---------------------------------------------------------------- stmat: fused sum_U + (Wv_h @ U_sum^T) + st_fix
__global__ __launch_bounds__(256) void stmat_kernel(
        const u16* __restrict__ U_part, const u16* __restrict__ wvb,
        const float* __restrict__ pnorm, const float* __restrict__ bkv,
        u16* __restrict__ st_red) {
    __shared__ u16 u_lds[32 * 1024];    // 64 KB, chunk-swizzled: phys = (e>>3) ^ (m&7)
    __shared__ u16 wv_lds[128 * 32];    // 8 KB
    __shared__ float norm[MM];
    const int bh = blockIdx.x, b = bh >> 3, h = bh & 7;
    const int t = threadIdx.x, l = t & 63, w = t >> 6;

    if (t < MM) {
        float s = 0.f;
        for (int g = 0; g < 64; g++) s += pnorm[((size_t)bh * 64 + g) * MM + t];
        norm[t] = s;
    }
    // phase 1: sum 16 partials; m-loop, e4 = t
    for (int m = 0; m < MM; m++) {
        const u16* src = U_part + ((size_t)(b * 256 + h * 32 + m)) * 1024 + t * 4;
        float4 s = make_float4(0.f, 0.f, 0.f, 0.f);
#pragma unroll
        for (int ks = 0; ks < 16; ks++) {
            const ushort4 v = *(const ushort4*)(src + (size_t)ks * 1048576);
            s.x += bf2f(v.x); s.y += bf2f(v.y); s.z += bf2f(v.z); s.w += bf2f(v.w);
        }
        ushort4 o; o.x = f2bf(s.x); o.y = f2bf(s.y); o.z = f2bf(s.z); o.w = f2bf(s.w);
        const int phys = (t >> 1) ^ (m & 7);
        *(ushort4*)&u_lds[m * 1024 + phys * 8 + (t & 1) * 4] = o;
    }

    // phase 2: 4 waves x 32 d-rows; acc[df][mf]
    f32x4 acc[2][2];
    const f32x4 zero = {0.f, 0.f, 0.f, 0.f};
    acc[0][0] = zero; acc[0][1] = zero; acc[1][0] = zero; acc[1][1] = zero;
    const int m16 = l & 15, kg = (l >> 4) * 8;

    for (int kt = 0; kt < 32; kt++) {
        __syncthreads();    // phase-1 done (kt=0) / readers done (kt>0)
        {
            const u16* src = wvb + (size_t)(h * 128 + (t >> 2)) * 1024 + kt * 32 + (t & 3) * 8;
            gload16(src, wv_lds + w * 512 + l * 8);
            gload16(src + (size_t)64 * 1024, wv_lds + 2048 + w * 512 + l * 8);
        }
        __syncthreads();    // staged (vmcnt drained by syncthreads)

        short8 a0 = *(const short8*)&wv_lds[(w * 32 + m16) * 32 + kg];
        short8 a1 = *(const short8*)&wv_lds[(w * 32 + 16 + m16) * 32 + kg];
        const int c0 = (((kt * 4 + (l >> 4)) ^ (m16 & 7)) << 3);
        short8 b0 = *(const short8*)&u_lds[m16 * 1024 + c0];
        short8 b1 = *(const short8*)&u_lds[(16 + m16) * 1024 + c0];
        acc[0][0] = MFMA16(a0, b0, acc[0][0]);
        acc[0][1] = MFMA16(a0, b1, acc[0][1]);
        acc[1][0] = MFMA16(a1, b0, acc[1][0]);
        acc[1][1] = MFMA16(a1, b1, acc[1][1]);
    }

    // epilogue: d = w*32 + df*16 + cr + q, m = mf*16 + cc
    const int cr = (l >> 4) << 2;
    const int cc = l & 15;
#pragma unroll
    for (int df = 0; df < 2; df++)
#pragma unroll
        for (int mf = 0; mf < 2; mf++)
#pragma unroll
            for (int q = 0; q < 4; q++) {
                const int d = w * 32 + df * 16 + cr + q;
                const int m = mf * 16 + cc;
                const float nv = norm[m];
                const float v = (acc[df][mf][q] + bkv[1024 + h * 128 + d] * nv) / (nv + 1e-5f);
                st_red[(size_t)bh * 4096 + m * 128 + d] = f2bf(v);
            }
}

// ---------------------------------------------------------------- qt_kernel
__global__ __launch_bounds__(256) void qt_kernel(const u16* __restrict__ st_red,
                                                 const float* __restrict__ qkvp,
                                                 float* __restrict__ qt_g) {
    __shared__ u16 st_lds[MM * DD];
    const int es = blockIdx.x, bh = blockIdx.y, h = bh & 7, t = threadIdx.x;
    {
        const uint4* src = (const uint4*)(st_red + (size_t)bh * 4096);
        ((uint4*)st_lds)[t] = src[t];
        ((uint4*)st_lds)[t + 256] = src[t + 256];
    }
    __syncthreads();
    const float* qw = qkvp + (size_t)h * DD * 384;
#pragma unroll
    for (int i = 0; i < 4; i++) {
        const int idx = t + i * 256;
        const int m = idx >> 5, el = idx & 31;
        const int e = es * 32 + el;
        float s = 0.f;
        for (int d = 0; d < DD; d++) s += bf2f(st_lds[m * DD + d]) * qw[d * 384 + e];
        qt_g[((size_t)bh * MM + m) * 384 + e] = s;
    }
}

// ---------------------------------------------------------------- finalize2 (per b,h)
__global__ void finalize2_kernel(const float* __restrict__ qt_g,
                                 float* __restrict__ attn_out, float* __restrict__ otw) {
    __shared__ float qt[MM * 384];
    __shared__ float dots[MM * MM];
    const int bh = blockIdx.x, t = threadIdx.x;

#pragma unroll
    for (int i = 0; i < 12; i++)
        ((float4*)qt)[t + i * 256] = ((const float4*)(qt_g + (size_t)bh * 12288))[t + i * 256];
    __syncthreads();
    const float scale = 0.08838834764831845f;
#pragma unroll
    for (int i = 0; i < 4; i++) {
        int idx = t * 4 + i;
        int qi = idx >> 5, kj = idx & 31;
        float s = 0.f;
        for (int d = 0; d < DD; d++) s += qt[qi * 384 + d] * qt[kj * 384 + 128 + d];
        dots[idx] = s * scale;
    }
    __syncthreads();
    if (t < MM) {
        float mx = -1e30f;
        float ex[MM];
#pragma unroll
        for (int j = 0; j < MM; j++) mx = fmaxf(mx, dots[t * MM + j]);
        float sm = 0.f;
#pragma unroll
        for (int j = 0; j < MM; j++) { ex[j] = __expf(dots[t * MM + j] - mx); sm += ex[j]; }
        float inv = 1.f / sm;
#pragma unroll
        for (int j = 0; j < MM; j++) {
            float v = ex[j] * inv;
            dots[t * MM + j] = v;
            attn_out[((size_t)bh * MM + t) * MM + j] = v;
        }
    }
    __syncthreads();
#pragma unroll
    for (int i = 0; i < 16; i++) {
        int e = t + i * 256;
        int m = e >> 7, d = e & 127;
        float s = 0.f;
#pragma unroll
        for (int j = 0; j < MM; j++) s += dots[m * MM + j] * qt[j * 384 + 256 + d];
        otw[(size_t)bh * 4096 + e] = s;
    }
}

// ---------------------------------------------------------------- zmat
__global__ __launch_bounds__(256) void zmat_kernel(const float* __restrict__ otw,
                                                   const float* __restrict__ outw,
                                                   u16* __restrict__ Zt) {
    __shared__ float ot_lds[MM * DD];
    const int bh = blockIdx.y, b = bh >> 3, h = bh & 7;
    const int es = blockIdx.x;
    const int t = threadIdx.x;
    for (int i = t; i < MM * DD; i += 256) ot_lds[i] = otw[(size_t)bh * 4096 + i];
    __syncthreads();
    const int e = es * 128 + (t >> 1);
    const int m0 = (t & 1) * 16;
    const float* ow = outw + (size_t)e * HDIM + h * DD;
    float acc[16];
#pragma unroll
    for (int m = 0; m < 16; m++) acc[m] = 0.f;
    for (int d = 0; d < DD; d += 4) {
        float4 o4 = *(const float4*)&ow[d];
#pragma unroll
        for (int m = 0; m < 16; m++) {
            const float* otr = &ot_lds[(m0 + m) * DD + d];
            acc[m] += o4.x * otr[0] + o4.y * otr[1] + o4.z * otr[2] + o4.w * otr[3];
        }
    }
    u32 pk[8];
#pragma unroll
    for (int p = 0; p < 8; p++)
        pk[p] = (u32)f2bf(acc[2 * p]) | ((u32)f2bf(acc[2 * p + 1]) << 16);
    u16* dst = Zt + ((size_t)b * 1024 + e) * 256 + h * MM + m0;
#pragma unroll
    for (int p = 0; p < 2; p++) {
        uint4 q4; q4.x = pk[4 * p]; q4.y = pk[4 * p + 1]; q4.z = pk[4 * p + 2]; q4.w = pk[4 * p + 3];
        *(uint4*)&dst[p * 8] = q4;
    }
}

// ---------------------------------------------------------------- launch
extern "C" void kernel_launch(void* const* d_in, const int* in_sizes, int n_in,
                              void* d_out, int out_size, void* d_ws, size_t ws_size,
                              hipStream_t stream) {
    const float* x        = (const float*)d_in[0];
    const float* wkv      = (const float*)d_in[1];
    const float* bkv      = (const float*)d_in[2];
    const float* wtq      = (const float*)d_in[3];
    const float* wtq_bias = (const float*)d_in[4];
    const float* qkvp     = (const float*)d_in[5];
    const float* outw     = (const float*)d_in[6];
    const float* outb     = (const float*)d_in[7];

    float* out  = (float*)d_out;
    float* out0 = out;                      // [B,N,HD]
    float* out1 = out + 67108864;           // slice_weights
    float* out2 = out + 83886080;           // temperature + bias
    float* out4 = out + 83886337;           // attn_weights

    char* ws = (char*)d_ws;
    u16*   xb     = (u16*)(ws);                         // 134 MB
    u16*   xbT    = (u16*)(ws + 134217728);             // 134 MB [b][e][n]
    u16*   wN     = (u16*)(ws + 268435456);             // 33.5 MB [b*256+hm][n]
    u16*   wT     = (u16*)(ws + 301989888);             // 33.5 MB [b*16384+n][256 hm]
    u16*   U_part = (u16*)(ws + 335544320);             // 33.5 MB (16 x 1024x1024 bf16)
    u16*   wvb    = (u16*)(ws + 409468928);             // 2 MB
    u16*   WQb    = (u16*)(ws + 411566080);             // 512 KB
    float* wqbias = (float*)(ws + 412090368);           // 1 KB
    float* pnorm  = (float*)(ws + 412091392);           // 256 KB
    u16*   st_red = (u16*)(ws + 412353536);             // 256 KB
    float* otws   = (float*)(ws + 412615680);           // 512 KB
    u16*   Zt     = (u16*)(ws + 413138944);             // 2 MB
    float* qt_g   = (float*)(ws + 415236096);           // 1.5 MB

    convert_kernel<<<dim3(4096), dim3(256), 0, stream>>>(x, xb, xbT, wtq_bias, out2);
    wq_kernel<<<dim3(8, 8), dim3(256), 0, stream>>>(wtq, wkv, bkv, WQb, wqbias, wvb);
    // fused: scores GEMM + softmax + weight outputs
    gemm_score_sm<<<dim3(256), dim3(512), 0, stream>>>(xb, WQb, wqbias, out1, wN, wT, pnorm);
    // U = w @ x : 8-phase, split-K x16 over n (Kd=1024 each), bf16 partials
    gemm_nt<2><<<dim3(16, 16), dim3(512), 0, stream>>>(wN, xbT, nullptr, (void*)U_part,
                                                       1024, 1024, 16384, 4, 0, 0,
                                                       (long long)16777216, (long long)1048576);
    // fused: sum U partials + Wv@U^T + st normalization
    stmat_kernel<<<dim3(32), dim3(256), 0, stream>>>(U_part, wvb, pnorm, bkv, st_red);
    qt_kernel<<<dim3(12, 32), dim3(256), 0, stream>>>(st_red, qkvp, qt_g);
    finalize2_kernel<<<dim3(32), dim3(256), 0, stream>>>(qt_g, out4, otws);
    zmat_kernel<<<dim3(8, 32), dim3(256), 0, stream>>>(otws, outw, Zt);
    // out0 = wT @ Zt^T (+outb), 128^2 tiles
    gemm_small<<<dim3(4096), dim3(256), 0, stream>>>(wT, Zt, outb, out0,
                                                     1024, 256, 256, 8, 7,
                                                     (long long)262144, 0);
}

// Round 19
// 505.363 us; speedup vs baseline: 1.0110x; 1.0110x over previous
//
#include <hip/hip_runtime.h>
#include <hip/hip_bf16.h>
#include <stdint.h>

#define BB 4
#define NN 16384
#define HDIM 1024
#define HH 8
#define MM 32
#define DD 128

typedef unsigned int u32;
typedef unsigned short u16;
typedef __attribute__((ext_vector_type(8))) short short8;
typedef __attribute__((ext_vector_type(4))) float f32x4;

__device__ __forceinline__ float bf2f(u16 v) {
    union { u32 u; float f; } c; c.u = ((u32)v) << 16; return c.f;
}
__device__ __forceinline__ u16 f2bf(float f) {
    union { float f; u32 u; } c; c.f = f;
    u32 r = c.u + 0x7fffu + ((c.u >> 16) & 1u);
    return (u16)(r >> 16);
}

__device__ __forceinline__ void gload16(const u16* g, u16* l) {
    __builtin_amdgcn_global_load_lds(
        (const __attribute__((address_space(1))) void*)g,
        (__attribute__((address_space(3))) void*)l, 16, 0, 0);
}

#define MFMA16(a, b, c) __builtin_amdgcn_mfma_f32_16x16x32_bf16(a, b, c, 0, 0, 0)

// ---------------------------------------------------------------- convert + transpose
__global__ __launch_bounds__(256) void convert_kernel(const float* __restrict__ x,
                                                      u16* __restrict__ xb, u16* __restrict__ xbT,
                                                      const float* __restrict__ wtq_bias,
                                                      float* __restrict__ out_misc) {
    __shared__ u32 tl[128 * 65];
    const int t = threadIdx.x;
    const int eb = blockIdx.x & 7;
    const int nb = blockIdx.x >> 3;
    const size_t n0 = (size_t)nb * 128;
    const int e0 = eb * 128;

#pragma unroll 4
    for (int i = 0; i < 32; i++) {
        const int idx = t + i * 256;
        const int nl = idx >> 6, e2 = idx & 63;
        const float2 v = *(const float2*)&x[(n0 + nl) * 1024 + e0 + e2 * 2];
        const u32 pk = (u32)f2bf(v.x) | ((u32)f2bf(v.y) << 16);
        ((u32*)xb)[((n0 + nl) * 1024 + e0) / 2 + e2] = pk;
        tl[nl * 65 + e2] = pk;
    }
    __syncthreads();
    const int b = (int)(n0 >> 14);
    const int nloc = (int)(n0 & 16383);
#pragma unroll 4
    for (int i = 0; i < 32; i++) {
        const int idx = t + i * 256;
        const int el = idx >> 6, n2 = idx & 63;
        const u32 w0 = tl[(2 * n2) * 65 + (el >> 1)];
        const u32 w1 = tl[(2 * n2 + 1) * 65 + (el >> 1)];
        const int sh = (el & 1) * 16;
        const u32 o = ((w0 >> sh) & 0xffffu) | (((w1 >> sh) & 0xffffu) << 16);
        ((u32*)xbT)[((size_t)(b * 1024 + e0 + el) * 16384 + nloc + 2 * n2) >> 1] = o;
    }
    if (blockIdx.x == 0) {
        if (t == 0) out_misc[0] = 1.0f;
        if (t < HH * MM) out_misc[1 + t] = wtq_bias[t];
    }
}

// ---------------------------------------------------------------- WQ = wtq @ Wkv_K ; wq_bias; Wv -> bf16
__global__ __launch_bounds__(256) void wq_kernel(const float* __restrict__ wtq,
                                                 const float* __restrict__ wkv,
                                                 const float* __restrict__ bkv,
                                                 u16* __restrict__ WQb, float* __restrict__ wqbias,
                                                 u16* __restrict__ wvb) {
    __shared__ float wtql[MM * DD];
    const int ec = blockIdx.x, h = blockIdx.y, t = threadIdx.x;
    for (int i = t; i < MM * DD; i += 256) wtql[i] = wtq[(size_t)h * MM * DD + i];
    __syncthreads();
    const int m = t >> 3;
    const int e = ec * 128 + (t & 7) * 16;
    float acc[16];
#pragma unroll
    for (int j = 0; j < 16; j++) acc[j] = 0.f;
    for (int d = 0; d < DD; d++) {
        const float wv = wtql[m * DD + d];
        const float4* row = (const float4*)(wkv + (size_t)(h * DD + d) * HDIM + e);
#pragma unroll
        for (int j4 = 0; j4 < 4; j4++) {
            float4 v = row[j4];
            acc[j4 * 4 + 0] += wv * v.x; acc[j4 * 4 + 1] += wv * v.y;
            acc[j4 * 4 + 2] += wv * v.z; acc[j4 * 4 + 3] += wv * v.w;
        }
    }
    u32 pk[8];
#pragma unroll
    for (int p = 0; p < 8; p++)
        pk[p] = (u32)f2bf(acc[2 * p]) | ((u32)f2bf(acc[2 * p + 1]) << 16);
    u16* dst = WQb + (size_t)(h * MM + m) * HDIM + e;
#pragma unroll
    for (int p = 0; p < 2; p++) {
        uint4 q4; q4.x = pk[4 * p]; q4.y = pk[4 * p + 1]; q4.z = pk[4 * p + 2]; q4.w = pk[4 * p + 3];
        *(uint4*)&dst[p * 8] = q4;
    }
    if (ec == 0 && t < MM) {
        float s = 0.f;
        for (int d = 0; d < DD; d++) s += wtql[t * DD + d] * bkv[h * DD + d];
        wqbias[h * MM + t] = s;
    }
    {
        const int blk = blockIdx.y * 8 + blockIdx.x;
        const float4* src = (const float4*)(wkv + (size_t)1024 * 1024);
        for (int i = t; i < 4096; i += 256) {
            const int idx4 = blk * 4096 + i;
            float4 v = src[idx4];
            ushort4 o; o.x = f2bf(v.x); o.y = f2bf(v.y); o.z = f2bf(v.z); o.w = f2bf(v.w);
            ((ushort4*)wvb)[idx4] = o;
        }
    }
}

// ---------------------------------------------------------------- fused scores GEMM + softmax
__global__ __launch_bounds__(512, 1) void gemm_score_sm(
        const u16* __restrict__ A, const u16* __restrict__ Bm,
        const float* __restrict__ bias,
        float* __restrict__ sw_out, u16* __restrict__ wN, u16* __restrict__ wT,
        float* __restrict__ pnorm) {
    __shared__ u16 smem[65536];
    const int t = threadIdx.x, l = t & 63, w = t >> 6;
    const int wr = w >> 2, wc = w & 3;

    const int nwg = gridDim.x, cpx = nwg >> 3, bid = blockIdx.x;
    const int tm = (bid & 7) * cpx + (bid >> 3);   // ntn = 1

    f32x4 acc[8][4];
    const f32x4 zero = {0.f, 0.f, 0.f, 0.f};
#pragma unroll
    for (int mi = 0; mi < 8; mi++)
#pragma unroll
        for (int ni = 0; ni < 4; ni++) acc[mi][ni] = zero;

    const int srow = w * 8 + (l >> 3);
    const int skel = ((l & 7) ^ ((l >> 3) & 7)) * 8;
    const u16* gA = A  + (size_t)(tm * 256 + srow) * 1024 + skel;
    const u16* gB = Bm + (size_t)srow * 1024 + skel;
    const int ldo = w * 512 + l * 8;

#define LAp(SL, H) (&smem[(SL) * 16384 + (H) * 8192])
#define LBp(SL, H) (&smem[32768 + (SL) * 16384 + (H) * 8192])
#define STAGE_A(T, H) { const u16* g_ = gA + (size_t)((H) * 128) * 1024 + (T) * 64; \
    u16* d_ = LAp((T) & 1, H) + ldo; gload16(g_, d_); gload16(g_ + (size_t)64 * 1024, d_ + 4096); }
#define STAGE_B(T, H) { const u16* g_ = gB + (size_t)((H) * 128) * 1024 + (T) * 64; \
    u16* d_ = LBp((T) & 1, H) + ldo; gload16(g_, d_); gload16(g_ + (size_t)64 * 1024, d_ + 4096); }

    const int m16 = l & 15;
    const int ck0 = (((l >> 4) + 0) ^ (l & 7)) << 3;
    const int ck1 = (((l >> 4) + 4) ^ (l & 7)) << 3;
    const int brb = (wc & 1) * 64;
    const int nT = 16;

    STAGE_A(0, 0); STAGE_A(0, 1); STAGE_B(0, 0); STAGE_B(0, 1);
    STAGE_B(1, 0); STAGE_B(1, 1);
    asm volatile("s_waitcnt vmcnt(4)" ::: "memory");
    __builtin_amdgcn_s_barrier();

    for (int kt = 0; kt < nT; ++kt) {
        const int sl = kt & 1;
        const u16* lA = LAp(sl, wr);
        const u16* lB = LBp(sl, wc >> 1);
        short8 aF[4][2], bF[4][2];

#pragma unroll
        for (int fr = 0; fr < 4; fr++) {
            aF[fr][0] = *(const short8*)&lA[(fr * 16 + m16) * 64 + ck0];
            aF[fr][1] = *(const short8*)&lA[(fr * 16 + m16) * 64 + ck1];
        }
#pragma unroll
        for (int fc = 0; fc < 2; fc++) {
            bF[fc][0] = *(const short8*)&lB[(brb + fc * 16 + m16) * 64 + ck0];
            bF[fc][1] = *(const short8*)&lB[(brb + fc * 16 + m16) * 64 + ck1];
        }
        if (kt + 1 < nT) STAGE_A(kt + 1, 0);
        __builtin_amdgcn_s_barrier();
        asm volatile("s_waitcnt lgkmcnt(0)" ::: "memory");
        __builtin_amdgcn_s_setprio(1);
#pragma unroll
        for (int kk = 0; kk < 2; kk++)
#pragma unroll
            for (int mi = 0; mi < 4; mi++) {
                acc[mi][0] = MFMA16(aF[mi][kk], bF[0][kk], acc[mi][0]);
                acc[mi][1] = MFMA16(aF[mi][kk], bF[1][kk], acc[mi][1]);
            }
        __builtin_amdgcn_s_setprio(0);
        __builtin_amdgcn_s_barrier();

#pragma unroll
        for (int fc = 2; fc < 4; fc++) {
            bF[fc][0] = *(const short8*)&lB[(brb + fc * 16 + m16) * 64 + ck0];
            bF[fc][1] = *(const short8*)&lB[(brb + fc * 16 + m16) * 64 + ck1];
        }
        if (kt + 1 < nT) STAGE_A(kt + 1, 1);
        __builtin_amdgcn_s_barrier();
        asm volatile("s_waitcnt lgkmcnt(0)" ::: "memory");
        __builtin_amdgcn_s_setprio(1);
#pragma unroll
        for (int kk = 0; kk < 2; kk++)
#pragma unroll
            for (int mi = 0; mi < 4; mi++) {
                acc[mi][2] = MFMA16(aF[mi][kk], bF[2][kk], acc[mi][2]);
                acc[mi][3] = MFMA16(aF[mi][kk], bF[3][kk], acc[mi][3]);
            }
        __builtin_amdgcn_s_setprio(0);
        __builtin_amdgcn_s_barrier();

#pragma unroll
        for (int fr = 0; fr < 4; fr++) {
            aF[fr][0] = *(const short8*)&lA[((fr + 4) * 16 + m16) * 64 + ck0];
            aF[fr][1] = *(const short8*)&lA[((fr + 4) * 16 + m16) * 64 + ck1];
        }
        if (kt + 2 < nT) STAGE_B(kt + 2, 0);
        __builtin_amdgcn_s_barrier();
        asm volatile("s_waitcnt lgkmcnt(0)" ::: "memory");
        __builtin_amdgcn_s_setprio(1);
#pragma unroll
        for (int kk = 0; kk < 2; kk++)
#pragma unroll
            for (int mi = 0; mi < 4; mi++) {
                acc[4 + mi][0] = MFMA16(aF[mi][kk], bF[0][kk], acc[4 + mi][0]);
                acc[4 + mi][1] = MFMA16(aF[mi][kk], bF[1][kk], acc[4 + mi][1]);
            }
        __builtin_amdgcn_s_setprio(0);
        __builtin_amdgcn_s_barrier();

        if (kt + 2 < nT) STAGE_B(kt + 2, 1);
        __builtin_amdgcn_s_barrier();
        __builtin_amdgcn_s_setprio(1);
#pragma unroll
        for (int kk = 0; kk < 2; kk++)
#pragma unroll
            for (int mi = 0; mi < 4; mi++) {
                acc[4 + mi][2] = MFMA16(aF[mi][kk], bF[2][kk], acc[4 + mi][2]);
                acc[4 + mi][3] = MFMA16(aF[mi][kk], bF[3][kk], acc[4 + mi][3]);
            }
        __builtin_amdgcn_s_setprio(0);
        if (kt < nT - 1) {
            if (kt + 2 < nT) asm volatile("s_waitcnt vmcnt(4)" ::: "memory");
            else             asm volatile("s_waitcnt vmcnt(0)" ::: "memory");
            __builtin_amdgcn_s_barrier();
        }
    }
#undef STAGE_A
#undef STAGE_B
#undef LAp
#undef LBp

    // ---- epilogue: scores -> LDS sc[hm][n] (bf16, +bias), 8B-chunk XOR swizzle
    __syncthreads();
    const int cr = (l >> 4) * 4;
    const int cc = l & 15;
#pragma unroll
    for (int ni = 0; ni < 4; ni++) {
        const int hm = wc * 64 + ni * 16 + cc;
        const float bv = bias[hm];
#pragma unroll
        for (int mi = 0; mi < 8; mi++) {
            const int nb_ = wr * 128 + mi * 16 + cr;
            u32 lo = (u32)f2bf(acc[mi][ni][0] + bv) | ((u32)f2bf(acc[mi][ni][1] + bv) << 16);
            u32 hi = (u32)f2bf(acc[mi][ni][2] + bv) | ((u32)f2bf(acc[mi][ni][3] + bv) << 16);
            uint2 pk; pk.x = lo; pk.y = hi;
            *(uint2*)&smem[hm * 256 + (((nb_ >> 2) ^ (hm & 63)) << 2)] = pk;
        }
    }
    __syncthreads();

    // ---- softmax over m: thread t -> n = t&255, h in [hs, hs+4)
    const int b = tm >> 6, g = tm & 63;
    const int n_ = t & 255, hs = (t >> 8) * 4;
    const size_t gn = (size_t)g * 256 + n_;
    for (int h = hs; h < hs + 4; h++) {
        float sv[MM];
#pragma unroll
        for (int m = 0; m < MM; m++) {
            const int hm = h * 32 + m;
            sv[m] = bf2f(smem[hm * 256 + (((n_ >> 2) ^ (hm & 63)) << 2) + (n_ & 3)]);
        }
        float mx = sv[0];
#pragma unroll
        for (int m = 1; m < MM; m++) mx = fmaxf(mx, sv[m]);
        float sum = 0.f;
#pragma unroll
        for (int m = 0; m < MM; m++) { sv[m] = __expf(sv[m] - mx); sum += sv[m]; }
        const float inv = 1.f / sum;
        u32 wpk[16];
#pragma unroll
        for (int m = 0; m < MM; m++) {
            const float wv = sv[m] * inv;
            const int hm = h * 32 + m;
            const size_t row = (size_t)(b * 256 + hm);
            sw_out[row * NN + gn] = wv;
            const u16 wb = f2bf(wv);
            wN[row * NN + gn] = wb;
            smem[hm * 256 + (((n_ >> 2) ^ (hm & 63)) << 2) + (n_ & 3)] = wb;
            if (m & 1) wpk[m >> 1] |= ((u32)wb << 16); else wpk[m >> 1] = (u32)wb;
        }
        u16* wrow = wT + ((size_t)(b * NN) + gn) * 256 + h * 32;
#pragma unroll
        for (int p = 0; p < 4; p++) {
            uint4 q4; q4.x = wpk[4 * p]; q4.y = wpk[4 * p + 1]; q4.z = wpk[4 * p + 2]; q4.w = wpk[4 * p + 3];
            *(uint4*)&wrow[p * 8] = q4;
        }
    }
    __syncthreads();

    // ---- pnorm: thread t -> hm = t>>1, half = t&1 (128 n each)
    {
        const int hm2 = t >> 1, half = t & 1;
        float s = 0.f;
        for (int j = 0; j < 128; j++) {
            const int n2 = half * 128 + j;
            s += bf2f(smem[hm2 * 256 + (((n2 >> 2) ^ (hm2 & 63)) << 2) + (n2 & 3)]);
        }
        s += __shfl_xor(s, 1);
        if (half == 0)
            pnorm[((size_t)(b * 8 + (hm2 >> 5)) * 64 + g) * MM + (hm2 & 31)] = s;
    }
}

// ---------------------------------------------------------------- unified 8-phase GEMM (256x256), MODE 2 bf16 C
template<int MODE>
__global__ __launch_bounds__(512, 1) void gemm_nt(
        const u16* __restrict__ A, const u16* __restrict__ Bm,
        const float* __restrict__ bias, void* __restrict__ Cout,
        int NCols, int Kd, int ldk, int ntn, int bofs, int bshift,
        long long bstrideB, long long kCstride) {
    __shared__ u16 ldsA[2][2][8192];
    __shared__ u16 ldsB[2][2][8192];
    const int t = threadIdx.x, l = t & 63, w = t >> 6;
    const int wr = w >> 2, wc = w & 3;

    const int nwg = gridDim.x, cpx = nwg >> 3, bid = blockIdx.x;
    const int swz = (nwg >= 8) ? ((bid & 7) * cpx + (bid >> 3)) : bid;
    const int tm = swz / ntn, tn = swz % ntn;
    const int ks = blockIdx.y;
    const u16* Bb = Bm + (size_t)(tm >> bshift) * bstrideB;

    f32x4 acc[8][4];
    const f32x4 zero = {0.f, 0.f, 0.f, 0.f};
#pragma unroll
    for (int mi = 0; mi < 8; mi++)
#pragma unroll
        for (int ni = 0; ni < 4; ni++) acc[mi][ni] = zero;

    const int srow = w * 8 + (l >> 3);
    const int skel = ((l & 7) ^ ((l >> 3) & 7)) * 8;
    const u16* gA = A  + (size_t)(tm * 256 + srow) * ldk + (size_t)ks * Kd + skel;
    const u16* gB = Bb + (size_t)(tn * 256 + srow) * ldk + (size_t)ks * Kd + skel;
    const int ldo = w * 512 + l * 8;

#define STAGE_A(T, H) { const u16* g_ = gA + (size_t)((H) * 128) * ldk + (T) * 64; \
    u16* d_ = &ldsA[(T) & 1][H][ldo]; gload16(g_, d_); gload16(g_ + (size_t)64 * ldk, d_ + 4096); }
#define STAGE_B(T, H) { const u16* g_ = gB + (size_t)((H) * 128) * ldk + (T) * 64; \
    u16* d_ = &ldsB[(T) & 1][H][ldo]; gload16(g_, d_); gload16(g_ + (size_t)64 * ldk, d_ + 4096); }

    const int m16 = l & 15;
    const int ck0 = (((l >> 4) + 0) ^ (l & 7)) << 3;
    const int ck1 = (((l >> 4) + 4) ^ (l & 7)) << 3;
    const int brb = (wc & 1) * 64;
    const int nT = Kd >> 6;

    STAGE_A(0, 0); STAGE_A(0, 1); STAGE_B(0, 0); STAGE_B(0, 1);
    STAGE_B(1, 0); STAGE_B(1, 1);
    asm volatile("s_waitcnt vmcnt(4)" ::: "memory");
    __builtin_amdgcn_s_barrier();

    for (int kt = 0; kt < nT; ++kt) {
        const int sl = kt & 1;
        const u16* lA = ldsA[sl][wr];
        const u16* lB = ldsB[sl][wc >> 1];
        short8 aF[4][2], bF[4][2];

#pragma unroll
        for (int fr = 0; fr < 4; fr++) {
            aF[fr][0] = *(const short8*)&lA[(fr * 16 + m16) * 64 + ck0];
            aF[fr][1] = *(const short8*)&lA[(fr * 16 + m16) * 64 + ck1];
        }
#pragma unroll
        for (int fc = 0; fc < 2; fc++) {
            bF[fc][0] = *(const short8*)&lB[(brb + fc * 16 + m16) * 64 + ck0];
            bF[fc][1] = *(const short8*)&lB[(brb + fc * 16 + m16) * 64 + ck1];
        }
        if (kt + 1 < nT) STAGE_A(kt + 1, 0);
        __builtin_amdgcn_s_barrier();
        asm volatile("s_waitcnt lgkmcnt(0)" ::: "memory");
        __builtin_amdgcn_s_setprio(1);
#pragma unroll
        for (int kk = 0; kk < 2; kk++)
#pragma unroll
            for (int mi = 0; mi < 4; mi++) {
                acc[mi][0] = MFMA16(aF[mi][kk], bF[0][kk], acc[mi][0]);
                acc[mi][1] = MFMA16(aF[mi][kk], bF[1][kk], acc[mi][1]);
            }
        __builtin_amdgcn_s_setprio(0);
        __builtin_amdgcn_s_barrier();

#pragma unroll
        for (int fc = 2; fc < 4; fc++) {
            bF[fc][0] = *(const short8*)&lB[(brb + fc * 16 + m16) * 64 + ck0];
            bF[fc][1] = *(const short8*)&lB[(brb + fc * 16 + m16) * 64 + ck1];
        }
        if (kt + 1 < nT) STAGE_A(kt + 1, 1);
        __builtin_amdgcn_s_barrier();
        asm volatile("s_waitcnt lgkmcnt(0)" ::: "memory");
        __builtin_amdgcn_s_setprio(1);
#pragma unroll
        for (int kk = 0; kk < 2; kk++)
#pragma unroll
            for (int mi = 0; mi < 4; mi++) {
                acc[mi][2] = MFMA16(aF[mi][kk], bF[2][kk], acc[mi][2]);
                acc[mi][3] = MFMA16(aF[mi][kk], bF[3][kk], acc[mi][3]);
            }
        __builtin_amdgcn_s_setprio(0);
        __builtin_amdgcn_s_barrier();

#pragma unroll
        for (int fr = 0; fr < 4; fr++) {
            aF[fr][0] = *(const short8*)&lA[((fr + 4) * 16 + m16) * 64 + ck0];
            aF[fr][1] = *(const short8*)&lA[((fr + 4) * 16 + m16) * 64 + ck1];
        }
        if (kt + 2 < nT) STAGE_B(kt + 2, 0);
        __builtin_amdgcn_s_barrier();
        asm volatile("s_waitcnt lgkmcnt(0)" ::: "memory");
        __builtin_amdgcn_s_setprio(1);
#pragma unroll
        for (int kk = 0; kk < 2; kk++)
#pragma unroll
            for (int mi = 0; mi < 4; mi++) {
                acc[4 + mi][0] = MFMA16(aF[mi][kk], bF[0][kk], acc[4 + mi][0]);
                acc[4 + mi][1] = MFMA16(aF[mi][kk], bF[1][kk], acc[4 + mi][1]);
            }
        __builtin_amdgcn_s_setprio(0);
        __builtin_amdgcn_s_barrier();

        if (kt + 2 < nT) STAGE_B(kt + 2, 1);
        __builtin_amdgcn_s_barrier();
        __builtin_amdgcn_s_setprio(1);
#pragma unroll
        for (int kk = 0; kk < 2; kk++)
#pragma unroll
            for (int mi = 0; mi < 4; mi++) {
                acc[4 + mi][2] = MFMA16(aF[mi][kk], bF[2][kk], acc[4 + mi][2]);
                acc[4 + mi][3] = MFMA16(aF[mi][kk], bF[3][kk], acc[4 + mi][3]);
            }
        __builtin_amdgcn_s_setprio(0);
        if (kt < nT - 1) {
            if (kt + 2 < nT) asm volatile("s_waitcnt vmcnt(4)" ::: "memory");
            else             asm volatile("s_waitcnt vmcnt(0)" ::: "memory");
            __builtin_amdgcn_s_barrier();
        }
    }
#undef STAGE_A
#undef STAGE_B

    const int cr = (l >> 4) * 4;
    const int cc = l & 15;
    if (MODE == 2) {
        u16* Cp = (u16*)Cout + (size_t)ks * kCstride;
#pragma unroll
        for (int ni = 0; ni < 4; ni++) {
            const int col = tn * 256 + wc * 64 + ni * 16 + cc;
            const float bv = bias ? bias[col] : 0.0f;
#pragma unroll
            for (int mi = 0; mi < 8; mi++) {
                const int row0 = tm * 256 + wr * 128 + mi * 16 + cr;
#pragma unroll
                for (int q = 0; q < 4; q++)
                    Cp[(size_t)(row0 + q) * NCols + col] = f2bf(acc[mi][ni][q] + bv);
            }
        }
    } else {
        float* Cp = (float*)Cout + (size_t)ks * kCstride;
#pragma unroll
        for (int ni = 0; ni < 4; ni++) {
            const int col = tn * 256 + wc * 64 + ni * 16 + cc;
            const float bv = bias ? bias[col] : 0.0f;
#pragma unroll
            for (int mi = 0; mi < 8; mi++) {
                const int row0 = tm * 256 + wr * 128 + mi * 16 + cr;
#pragma unroll
                for (int q = 0; q < 4; q++)
                    Cp[(size_t)(row0 + q) * NCols + col] = acc[mi][ni][q] + bv;
            }
        }
    }
}

// ---------------------------------------------------------------- small 2-phase GEMM (128x128, BK=32, 16 KB LDS)
__global__ __launch_bounds__(256, 2) void gemm_small(
        const u16* __restrict__ A, const u16* __restrict__ Bm,
        const float* __restrict__ bias, float* __restrict__ Cout,
        int Ncols, int Kds, int ldk, int ntn, int bshift,
        long long bstrideB, long long kCstride) {
    __shared__ u16 lds_a[128 * 32];
    __shared__ u16 lds_b[128 * 32];
    const int t = threadIdx.x, l = t & 63, w = t >> 6;
    const int wr = w >> 1, wc = w & 1;

    const int nwg = gridDim.x, cpx = nwg >> 3, bid = blockIdx.x;
    const int swz = (nwg >= 8) ? ((bid & 7) * cpx + (bid >> 3)) : bid;
    const int tm = swz / ntn, tn = swz % ntn;
    const int ks = blockIdx.y;
    const u16* Bb = Bm + (size_t)(tm >> bshift) * bstrideB;

    f32x4 acc[4][4];
    const f32x4 zero = {0.f, 0.f, 0.f, 0.f};
#pragma unroll
    for (int mi = 0; mi < 4; mi++)
#pragma unroll
        for (int ni = 0; ni < 4; ni++) acc[mi][ni] = zero;

    const int srow = w * 32 + (l >> 2);
    const int scol = (l & 3) * 8;
    const u16* ga = A  + (size_t)(tm * 128 + srow) * ldk + (size_t)ks * Kds + scol;
    const u16* gb = Bb + (size_t)(tn * 128 + srow) * ldk + (size_t)ks * Kds + scol;
    u16* la = &lds_a[(w * 32) * 32];
    u16* lb = &lds_b[(w * 32) * 32];
    const size_t rstep = (size_t)16 * ldk;

    const int nK = Kds >> 5;
    const int kg = (l >> 4) * 8;
    const int ra = wr * 64 + (l & 15);
    const int rb = wc * 64 + (l & 15);

    for (int kt = 0; kt < nK; kt++) {
        __syncthreads();
        const int ko = kt << 5;
        gload16(ga + ko,         la);
        gload16(ga + ko + rstep, la + 16 * 32);
        gload16(gb + ko,         lb);
        gload16(gb + ko + rstep, lb + 16 * 32);
        __syncthreads();

        short8 af[4], bfr[4];
#pragma unroll
        for (int mi = 0; mi < 4; mi++) af[mi] = *(const short8*)&lds_a[(ra + mi * 16) * 32 + kg];
#pragma unroll
        for (int ni = 0; ni < 4; ni++) bfr[ni] = *(const short8*)&lds_b[(rb + ni * 16) * 32 + kg];
#pragma unroll
        for (int mi = 0; mi < 4; mi++)
#pragma unroll
            for (int ni = 0; ni < 4; ni++)
                acc[mi][ni] = MFMA16(af[mi], bfr[ni], acc[mi][ni]);
    }

    float* Cp = Cout + (size_t)ks * kCstride;
#pragma unroll
    for (int ni = 0; ni < 4; ni++) {
        const int col = tn * 128 + wc * 64 + ni * 16 + (l & 15);
        const float bv = bias ? bias[col] : 0.0f;
#pragma unroll
        for (int mi = 0; mi < 4; mi++) {
            const int row0 = tm * 128 + wr * 64 + mi * 16 + ((l >> 4) << 2);
#pragma unroll
            for (int q = 0; q < 4; q++)
                Cp[(size_t)(row0 + q) * Ncols + col] = acc[mi][ni][q] + bv;
        }
    }
}

// ---------------------------------------------------------------- sum U k-split bf16 partials (16) -> reordered bf16 U2
__global__ __launch_bounds__(256) void sum_U(const u16* __restrict__ U_part, u16* __restrict__ U2) {
    const int i = blockIdx.x * 256 + threadIdx.x;   // 262144 groups of 4 elems
    float4 s = make_float4(0.f, 0.f, 0.f, 0.f);
    for (int ks = 0; ks < 16; ks++) {
        const ushort4 v = ((const ushort4*)(U_part + (size_t)ks * 1048576))[i];
        s.x += bf2f(v.x); s.y += bf2f(v.y); s.z += bf2f(v.z); s.w += bf2f(v.w);
    }
    const int r = i >> 8, e4 = i & 255;
    const int b = r >> 8, h = (r >> 5) & 7, m = r & 31;
    const int r2 = h * 128 + b * 32 + m;
    ushort4 o; o.x = f2bf(s.x); o.y = f2bf(s.y); o.z = f2bf(s.z); o.w = f2bf(s.w);
    ((ushort4*)U2)[r2 * 256 + e4] = o;
}

// ---------------------------------------------------------------- st_fix: st_red = (sum_ks C2 + bv*norm)/(norm+eps), bf16
__global__ __launch_bounds__(256) void st_fix(const float* __restrict__ C2,
                                              const float* __restrict__ pnorm,
                                              const float* __restrict__ bkv,
                                              u16* __restrict__ st_red) {
    __shared__ float norm[MM];
    const int bh = blockIdx.x, b = bh >> 3, h = bh & 7, t = threadIdx.x;
    if (t < MM) {
        float s = 0.f;
        for (int g = 0; g < 64; g++) s += pnorm[((size_t)bh * 64 + g) * MM + t];
        norm[t] = s;
    }
    __syncthreads();
#pragma unroll
    for (int i = 0; i < 16; i++) {
        const int idx = t * 16 + i;
        const int m = idx >> 7, d = idx & 127;
        const float nv = norm[m];
        float c = 0.f;
        const size_t off = (size_t)(h * 128 + d) * 128 + b * 32 + m;
#pragma unroll
        for (int ks = 0; ks < 8; ks++) c += C2[(size_t)ks * 131072 + off];
        const float v = (c + bkv[1024 + h * 128 + d] * nv) / (nv + 1e-5f);
        st_red[(size_t)bh * 4096 + idx] = f2bf(v);
    }
}

// ---------------------------------------------------------------- qt_kernel
__global__ __launch_bounds__(256) void qt_kernel(const u16* __restrict__ st_red,
                                                 const float* __restrict__ qkvp,
                                                 float* __restrict__ qt_g) {
    __shared__ u16 st_lds[MM * DD];
    const int es = blockIdx.x, bh = blockIdx.y, h = bh & 7, t = threadIdx.x;
    {
        const uint4* src = (const uint4*)(st_red + (size_t)bh * 4096);
        ((uint4*)st_lds)[t] = src[t];
        ((uint4*)st_lds)[t + 256] = src[t + 256];
    }
    __syncthreads();
    const float* qw = qkvp + (size_t)h * DD * 384;
#pragma unroll
    for (int i = 0; i < 4; i++) {
        const int idx = t + i * 256;
        const int m = idx >> 5, el = idx & 31;
        const int e = es * 32 + el;
        float s = 0.f;
        for (int d = 0; d < DD; d++) s += bf2f(st_lds[m * DD + d]) * qw[d * 384 + e];
        qt_g[((size_t)bh * MM + m) * 384 + e] = s;
    }
}

// ---------------------------------------------------------------- finalize2 (per b,h)
__global__ void finalize2_kernel(const float* __restrict__ qt_g,
                                 float* __restrict__ attn_out, float* __restrict__ otw) {
    __shared__ float qt[MM * 384];
    __shared__ float dots[MM * MM];
    const int bh = blockIdx.x, t = threadIdx.x;

#pragma unroll
    for (int i = 0; i < 12; i++)
        ((float4*)qt)[t + i * 256] = ((const float4*)(qt_g + (size_t)bh * 12288))[t + i * 256];
    __syncthreads();
    const float scale = 0.08838834764831845f;
#pragma unroll
    for (int i = 0; i < 4; i++) {
        int idx = t * 4 + i;
        int qi = idx >> 5, kj = idx & 31;
        float s = 0.f;
        for (int d = 0; d < DD; d++) s += qt[qi * 384 + d] * qt[kj * 384 + 128 + d];
        dots[idx] = s * scale;
    }
    __syncthreads();
    if (t < MM) {
        float mx = -1e30f;
        float ex[MM];
#pragma unroll
        for (int j = 0; j < MM; j++) mx = fmaxf(mx, dots[t * MM + j]);
        float sm = 0.f;
#pragma unroll
        for (int j = 0; j < MM; j++) { ex[j] = __expf(dots[t * MM + j] - mx); sm += ex[j]; }
        float inv = 1.f / sm;
#pragma unroll
        for (int j = 0; j < MM; j++) {
            float v = ex[j] * inv;
            dots[t * MM + j] = v;
            attn_out[((size_t)bh * MM + t) * MM + j] = v;
        }
    }
    __syncthreads();
#pragma unroll
    for (int i = 0; i < 16; i++) {
        int e = t + i * 256;
        int m = e >> 7, d = e & 127;
        float s = 0.f;
#pragma unroll
        for (int j = 0; j < MM; j++) s += dots[m * MM + j] * qt[j * 384 + 256 + d];
        otw[(size_t)bh * 4096 + e] = s;
    }
}

// ---------------------------------------------------------------- zmat
__global__ __launch_bounds__(256) void zmat_kernel(const float* __restrict__ otw,
                                                   const float* __restrict__ outw,
                                                   u16* __restrict__ Zt) {
    __shared__ float ot_lds[MM * DD];
    const int bh = blockIdx.y, b = bh >> 3, h = bh & 7;
    const int es = blockIdx.x;
    const int t = threadIdx.x;
    for (int i = t; i < MM * DD; i += 256) ot_lds[i] = otw[(size_t)bh * 4096 + i];
    __syncthreads();
    const int e = es * 128 + (t >> 1);
    const int m0 = (t & 1) * 16;
    const float* ow = outw + (size_t)e * HDIM + h * DD;
    float acc[16];
#pragma unroll
    for (int m = 0; m < 16; m++) acc[m] = 0.f;
    for (int d = 0; d < DD; d += 4) {
        float4 o4 = *(const float4*)&ow[d];
#pragma unroll
        for (int m = 0; m < 16; m++) {
            const float* otr = &ot_lds[(m0 + m) * DD + d];
            acc[m] += o4.x * otr[0] + o4.y * otr[1] + o4.z * otr[2] + o4.w * otr[3];
        }
    }
    u32 pk[8];
#pragma unroll
    for (int p = 0; p < 8; p++)
        pk[p] = (u32)f2bf(acc[2 * p]) | ((u32)f2bf(acc[2 * p + 1]) << 16);
    u16* dst = Zt + ((size_t)b * 1024 + e) * 256 + h * MM + m0;
#pragma unroll
    for (int p = 0; p < 2; p++) {
        uint4 q4; q4.x = pk[4 * p]; q4.y = pk[4 * p + 1]; q4.z = pk[4 * p + 2]; q4.w = pk[4 * p + 3];
        *(uint4*)&dst[p * 8] = q4;
    }
}

// ---------------------------------------------------------------- launch
extern "C" void kernel_launch(void* const* d_in, const int* in_sizes, int n_in,
                              void* d_out, int out_size, void* d_ws, size_t ws_size,
                              hipStream_t stream) {
    const float* x        = (const float*)d_in[0];
    const float* wkv      = (const float*)d_in[1];
    const float* bkv      = (const float*)d_in[2];
    const float* wtq      = (const float*)d_in[3];
    const float* wtq_bias = (const float*)d_in[4];
    const float* qkvp     = (const float*)d_in[5];
    const float* outw     = (const float*)d_in[6];
    const float* outb     = (const float*)d_in[7];

    float* out  = (float*)d_out;
    float* out0 = out;                      // [B,N,HD]
    float* out1 = out + 67108864;           // slice_weights
    float* out2 = out + 83886080;           // temperature + bias
    float* out4 = out + 83886337;           // attn_weights

    char* ws = (char*)d_ws;
    u16*   xb     = (u16*)(ws);                         // 134 MB
    u16*   xbT    = (u16*)(ws + 134217728);             // 134 MB [b][e][n]
    u16*   wN     = (u16*)(ws + 268435456);             // 33.5 MB [b*256+hm][n]
    u16*   wT     = (u16*)(ws + 301989888);             // 33.5 MB [b*16384+n][256 hm]
    u16*   U_part = (u16*)(ws + 335544320);             // 33.5 MB (16 x 1024x1024 bf16)
    u16*   U2     = (u16*)(ws + 402653184);             // 2 MB [h*128+b*32+m][1024 e]
    float* C2     = (float*)(ws + 404750336);           // 4 MB (8 x 1024x128 f32)
    u16*   wvb    = (u16*)(ws + 409468928);             // 2 MB
    u16*   WQb    = (u16*)(ws + 411566080);             // 512 KB
    float* wqbias = (float*)(ws + 412090368);           // 1 KB
    float* pnorm  = (float*)(ws + 412091392);           // 256 KB
    u16*   st_red = (u16*)(ws + 412353536);             // 256 KB
    float* otws   = (float*)(ws + 412615680);           // 512 KB
    u16*   Zt     = (u16*)(ws + 413138944);             // 2 MB
    float* qt_g   = (float*)(ws + 415236096);           // 1.5 MB

    convert_kernel<<<dim3(4096), dim3(256), 0, stream>>>(x, xb, xbT, wtq_bias, out2);
    wq_kernel<<<dim3(8, 8), dim3(256), 0, stream>>>(wtq, wkv, bkv, WQb, wqbias, wvb);
    // fused: scores GEMM + softmax + weight outputs
    gemm_score_sm<<<dim3(256), dim3(512), 0, stream>>>(xb, WQb, wqbias, out1, wN, wT, pnorm);
    // U = w @ x : 8-phase, split-K x16 over n (Kd=1024 each), bf16 partials
    gemm_nt<2><<<dim3(16, 16), dim3(512), 0, stream>>>(wN, xbT, nullptr, (void*)U_part,
                                                       1024, 1024, 16384, 4, 0, 0,
                                                       (long long)16777216, (long long)1048576);
    sum_U<<<dim3(1024), dim3(256), 0, stream>>>(U_part, U2);
    // C2[ks][hd][b*32+m] = Wv_h @ U2_h^T, per-h diagonal tiles, split-K x8
    gemm_small<<<dim3(8, 8), dim3(256), 0, stream>>>(wvb, U2, nullptr, C2,
                                                     128, 128, 1024, 1, 0,
                                                     (long long)131072, (long long)131072);
    st_fix<<<dim3(32), dim3(256), 0, stream>>>(C2, pnorm, bkv, st_red);
    qt_kernel<<<dim3(12, 32), dim3(256), 0, stream>>>(st_red, qkvp, qt_g);
    finalize2_kernel<<<dim3(32), dim3(256), 0, stream>>>(qt_g, out4, otws);
    zmat_kernel<<<dim3(8, 32), dim3(256), 0, stream>>>(otws, outw, Zt);
    // out0 = wT @ Zt^T (+outb), 128^2 tiles
    gemm_small<<<dim3(4096), dim3(256), 0, stream>>>(wT, Zt, outb, out0,
                                                     1024, 256, 256, 8, 7,
                                                     (long long)262144, 0);
}

// Round 20
// 501.719 us; speedup vs baseline: 1.0184x; 1.0073x over previous
//
#include <hip/hip_runtime.h>
#include <hip/hip_bf16.h>
#include <stdint.h>

#define BB 4
#define NN 16384
#define HDIM 1024
#define HH 8
#define MM 32
#define DD 128

typedef unsigned int u32;
typedef unsigned short u16;
typedef __attribute__((ext_vector_type(8))) short short8;
typedef __attribute__((ext_vector_type(4))) float f32x4;

__device__ __forceinline__ float bf2f(u16 v) {
    union { u32 u; float f; } c; c.u = ((u32)v) << 16; return c.f;
}
__device__ __forceinline__ u16 f2bf(float f) {
    union { float f; u32 u; } c; c.f = f;
    u32 r = c.u + 0x7fffu + ((c.u >> 16) & 1u);
    return (u16)(r >> 16);
}

__device__ __forceinline__ void gload16(const u16* g, u16* l) {
    __builtin_amdgcn_global_load_lds(
        (const __attribute__((address_space(1))) void*)g,
        (__attribute__((address_space(3))) void*)l, 16, 0, 0);
}

#define MFMA16(a, b, c) __builtin_amdgcn_mfma_f32_16x16x32_bf16(a, b, c, 0, 0, 0)

// ---------------------------------------------------------------- convert + transpose
__global__ __launch_bounds__(256) void convert_kernel(const float* __restrict__ x,
                                                      u16* __restrict__ xb, u16* __restrict__ xbT,
                                                      const float* __restrict__ wtq_bias,
                                                      float* __restrict__ out_misc) {
    __shared__ u32 tl[128 * 65];
    const int t = threadIdx.x;
    const int eb = blockIdx.x & 7;
    const int nb = blockIdx.x >> 3;
    const size_t n0 = (size_t)nb * 128;
    const int e0 = eb * 128;

#pragma unroll 4
    for (int i = 0; i < 32; i++) {
        const int idx = t + i * 256;
        const int nl = idx >> 6, e2 = idx & 63;
        const float2 v = *(const float2*)&x[(n0 + nl) * 1024 + e0 + e2 * 2];
        const u32 pk = (u32)f2bf(v.x) | ((u32)f2bf(v.y) << 16);
        ((u32*)xb)[((n0 + nl) * 1024 + e0) / 2 + e2] = pk;
        tl[nl * 65 + e2] = pk;
    }
    __syncthreads();
    const int b = (int)(n0 >> 14);
    const int nloc = (int)(n0 & 16383);
#pragma unroll 4
    for (int i = 0; i < 32; i++) {
        const int idx = t + i * 256;
        const int el = idx >> 6, n2 = idx & 63;
        const u32 w0 = tl[(2 * n2) * 65 + (el >> 1)];
        const u32 w1 = tl[(2 * n2 + 1) * 65 + (el >> 1)];
        const int sh = (el & 1) * 16;
        const u32 o = ((w0 >> sh) & 0xffffu) | (((w1 >> sh) & 0xffffu) << 16);
        ((u32*)xbT)[((size_t)(b * 1024 + e0 + el) * 16384 + nloc + 2 * n2) >> 1] = o;
    }
    if (blockIdx.x == 0) {
        if (t == 0) out_misc[0] = 1.0f;
        if (t < HH * MM) out_misc[1 + t] = wtq_bias[t];
    }
}

// ---------------------------------------------------------------- WQ = wtq @ Wkv_K ; wq_bias; Wv -> bf16
__global__ __launch_bounds__(256) void wq_kernel(const float* __restrict__ wtq,
                                                 const float* __restrict__ wkv,
                                                 const float* __restrict__ bkv,
                                                 u16* __restrict__ WQb, float* __restrict__ wqbias,
                                                 u16* __restrict__ wvb) {
    __shared__ float wtql[MM * DD];
    const int ec = blockIdx.x, h = blockIdx.y, t = threadIdx.x;
    for (int i = t; i < MM * DD; i += 256) wtql[i] = wtq[(size_t)h * MM * DD + i];
    __syncthreads();
    const int m = t >> 3;
    const int e = ec * 128 + (t & 7) * 16;
    float acc[16];
#pragma unroll
    for (int j = 0; j < 16; j++) acc[j] = 0.f;
    for (int d = 0; d < DD; d++) {
        const float wv = wtql[m * DD + d];
        const float4* row = (const float4*)(wkv + (size_t)(h * DD + d) * HDIM + e);
#pragma unroll
        for (int j4 = 0; j4 < 4; j4++) {
            float4 v = row[j4];
            acc[j4 * 4 + 0] += wv * v.x; acc[j4 * 4 + 1] += wv * v.y;
            acc[j4 * 4 + 2] += wv * v.z; acc[j4 * 4 + 3] += wv * v.w;
        }
    }
    u32 pk[8];
#pragma unroll
    for (int p = 0; p < 8; p++)
        pk[p] = (u32)f2bf(acc[2 * p]) | ((u32)f2bf(acc[2 * p + 1]) << 16);
    u16* dst = WQb + (size_t)(h * MM + m) * HDIM + e;
#pragma unroll
    for (int p = 0; p < 2; p++) {
        uint4 q4; q4.x = pk[4 * p]; q4.y = pk[4 * p + 1]; q4.z = pk[4 * p + 2]; q4.w = pk[4 * p + 3];
        *(uint4*)&dst[p * 8] = q4;
    }
    if (ec == 0 && t < MM) {
        float s = 0.f;
        for (int d = 0; d < DD; d++) s += wtql[t * DD + d] * bkv[h * DD + d];
        wqbias[h * MM + t] = s;
    }
    {
        const int blk = blockIdx.y * 8 + blockIdx.x;
        const float4* src = (const float4*)(wkv + (size_t)1024 * 1024);
        for (int i = t; i < 4096; i += 256) {
            const int idx4 = blk * 4096 + i;
            float4 v = src[idx4];
            ushort4 o; o.x = f2bf(v.x); o.y = f2bf(v.y); o.z = f2bf(v.z); o.w = f2bf(v.w);
            ((ushort4*)wvb)[idx4] = o;
        }
    }
}

// ---------------------------------------------------------------- fused scores GEMM + softmax
__global__ __launch_bounds__(512, 1) void gemm_score_sm(
        const u16* __restrict__ A, const u16* __restrict__ Bm,
        const float* __restrict__ bias,
        float* __restrict__ sw_out, u16* __restrict__ wN, u16* __restrict__ wT,
        float* __restrict__ pnorm) {
    __shared__ u16 smem[65536];
    const int t = threadIdx.x, l = t & 63, w = t >> 6;
    const int wr = w >> 2, wc = w & 3;

    const int nwg = gridDim.x, cpx = nwg >> 3, bid = blockIdx.x;
    const int tm = (bid & 7) * cpx + (bid >> 3);   // ntn = 1

    f32x4 acc[8][4];
    const f32x4 zero = {0.f, 0.f, 0.f, 0.f};
#pragma unroll
    for (int mi = 0; mi < 8; mi++)
#pragma unroll
        for (int ni = 0; ni < 4; ni++) acc[mi][ni] = zero;

    const int srow = w * 8 + (l >> 3);
    const int skel = ((l & 7) ^ ((l >> 3) & 7)) * 8;
    const u16* gA = A  + (size_t)(tm * 256 + srow) * 1024 + skel;
    const u16* gB = Bm + (size_t)srow * 1024 + skel;
    const int ldo = w * 512 + l * 8;

#define LAp(SL, H) (&smem[(SL) * 16384 + (H) * 8192])
#define LBp(SL, H) (&smem[32768 + (SL) * 16384 + (H) * 8192])
#define STAGE_A(T, H) { const u16* g_ = gA + (size_t)((H) * 128) * 1024 + (T) * 64; \
    u16* d_ = LAp((T) & 1, H) + ldo; gload16(g_, d_); gload16(g_ + (size_t)64 * 1024, d_ + 4096); }
#define STAGE_B(T, H) { const u16* g_ = gB + (size_t)((H) * 128) * 1024 + (T) * 64; \
    u16* d_ = LBp((T) & 1, H) + ldo; gload16(g_, d_); gload16(g_ + (size_t)64 * 1024, d_ + 4096); }

    const int m16 = l & 15;
    const int ck0 = (((l >> 4) + 0) ^ (l & 7)) << 3;
    const int ck1 = (((l >> 4) + 4) ^ (l & 7)) << 3;
    const int brb = (wc & 1) * 64;
    const int nT = 16;

    STAGE_A(0, 0); STAGE_A(0, 1); STAGE_B(0, 0); STAGE_B(0, 1);
    STAGE_B(1, 0); STAGE_B(1, 1);
    asm volatile("s_waitcnt vmcnt(4)" ::: "memory");
    __builtin_amdgcn_s_barrier();

    for (int kt = 0; kt < nT; ++kt) {
        const int sl = kt & 1;
        const u16* lA = LAp(sl, wr);
        const u16* lB = LBp(sl, wc >> 1);
        short8 aF[4][2], bF[4][2];

#pragma unroll
        for (int fr = 0; fr < 4; fr++) {
            aF[fr][0] = *(const short8*)&lA[(fr * 16 + m16) * 64 + ck0];
            aF[fr][1] = *(const short8*)&lA[(fr * 16 + m16) * 64 + ck1];
        }
#pragma unroll
        for (int fc = 0; fc < 2; fc++) {
            bF[fc][0] = *(const short8*)&lB[(brb + fc * 16 + m16) * 64 + ck0];
            bF[fc][1] = *(const short8*)&lB[(brb + fc * 16 + m16) * 64 + ck1];
        }
        if (kt + 1 < nT) STAGE_A(kt + 1, 0);
        __builtin_amdgcn_s_barrier();
        asm volatile("s_waitcnt lgkmcnt(0)" ::: "memory");
        __builtin_amdgcn_s_setprio(1);
#pragma unroll
        for (int kk = 0; kk < 2; kk++)
#pragma unroll
            for (int mi = 0; mi < 4; mi++) {
                acc[mi][0] = MFMA16(aF[mi][kk], bF[0][kk], acc[mi][0]);
                acc[mi][1] = MFMA16(aF[mi][kk], bF[1][kk], acc[mi][1]);
            }
        __builtin_amdgcn_s_setprio(0);
        __builtin_amdgcn_s_barrier();

#pragma unroll
        for (int fc = 2; fc < 4; fc++) {
            bF[fc][0] = *(const short8*)&lB[(brb + fc * 16 + m16) * 64 + ck0];
            bF[fc][1] = *(const short8*)&lB[(brb + fc * 16 + m16) * 64 + ck1];
        }
        if (kt + 1 < nT) STAGE_A(kt + 1, 1);
        __builtin_amdgcn_s_barrier();
        asm volatile("s_waitcnt lgkmcnt(0)" ::: "memory");
        __builtin_amdgcn_s_setprio(1);
#pragma unroll
        for (int kk = 0; kk < 2; kk++)
#pragma unroll
            for (int mi = 0; mi < 4; mi++) {
                acc[mi][2] = MFMA16(aF[mi][kk], bF[2][kk], acc[mi][2]);
                acc[mi][3] = MFMA16(aF[mi][kk], bF[3][kk], acc[mi][3]);
            }
        __builtin_amdgcn_s_setprio(0);
        __builtin_amdgcn_s_barrier();

#pragma unroll
        for (int fr = 0; fr < 4; fr++) {
            aF[fr][0] = *(const short8*)&lA[((fr + 4) * 16 + m16) * 64 + ck0];
            aF[fr][1] = *(const short8*)&lA[((fr + 4) * 16 + m16) * 64 + ck1];
        }
        if (kt + 2 < nT) STAGE_B(kt + 2, 0);
        __builtin_amdgcn_s_barrier();
        asm volatile("s_waitcnt lgkmcnt(0)" ::: "memory");
        __builtin_amdgcn_s_setprio(1);
#pragma unroll
        for (int kk = 0; kk < 2; kk++)
#pragma unroll
            for (int mi = 0; mi < 4; mi++) {
                acc[4 + mi][0] = MFMA16(aF[mi][kk], bF[0][kk], acc[4 + mi][0]);
                acc[4 + mi][1] = MFMA16(aF[mi][kk], bF[1][kk], acc[4 + mi][1]);
            }
        __builtin_amdgcn_s_setprio(0);
        __builtin_amdgcn_s_barrier();

        if (kt + 2 < nT) STAGE_B(kt + 2, 1);
        __builtin_amdgcn_s_barrier();
        __builtin_amdgcn_s_setprio(1);
#pragma unroll
        for (int kk = 0; kk < 2; kk++)
#pragma unroll
            for (int mi = 0; mi < 4; mi++) {
                acc[4 + mi][2] = MFMA16(aF[mi][kk], bF[2][kk], acc[4 + mi][2]);
                acc[4 + mi][3] = MFMA16(aF[mi][kk], bF[3][kk], acc[4 + mi][3]);
            }
        __builtin_amdgcn_s_setprio(0);
        if (kt < nT - 1) {
            if (kt + 2 < nT) asm volatile("s_waitcnt vmcnt(4)" ::: "memory");
            else             asm volatile("s_waitcnt vmcnt(0)" ::: "memory");
            __builtin_amdgcn_s_barrier();
        }
    }
#undef STAGE_A
#undef STAGE_B
#undef LAp
#undef LBp

    // ---- epilogue: scores -> LDS sc[hm][n] (bf16, +bias), 8B-chunk XOR swizzle
    __syncthreads();
    const int cr = (l >> 4) * 4;
    const int cc = l & 15;
#pragma unroll
    for (int ni = 0; ni < 4; ni++) {
        const int hm = wc * 64 + ni * 16 + cc;
        const float bv = bias[hm];
#pragma unroll
        for (int mi = 0; mi < 8; mi++) {
            const int nb_ = wr * 128 + mi * 16 + cr;
            u32 lo = (u32)f2bf(acc[mi][ni][0] + bv) | ((u32)f2bf(acc[mi][ni][1] + bv) << 16);
            u32 hi = (u32)f2bf(acc[mi][ni][2] + bv) | ((u32)f2bf(acc[mi][ni][3] + bv) << 16);
            uint2 pk; pk.x = lo; pk.y = hi;
            *(uint2*)&smem[hm * 256 + (((nb_ >> 2) ^ (hm & 63)) << 2)] = pk;
        }
    }
    __syncthreads();

    // ---- softmax over m: thread t -> n = t&255, h in [hs, hs+4)
    const int b = tm >> 6, g = tm & 63;
    const int n_ = t & 255, hs = (t >> 8) * 4;
    const size_t gn = (size_t)g * 256 + n_;
    for (int h = hs; h < hs + 4; h++) {
        float sv[MM];
#pragma unroll
        for (int m = 0; m < MM; m++) {
            const int hm = h * 32 + m;
            sv[m] = bf2f(smem[hm * 256 + (((n_ >> 2) ^ (hm & 63)) << 2) + (n_ & 3)]);
        }
        float mx = sv[0];
#pragma unroll
        for (int m = 1; m < MM; m++) mx = fmaxf(mx, sv[m]);
        float sum = 0.f;
#pragma unroll
        for (int m = 0; m < MM; m++) { sv[m] = __expf(sv[m] - mx); sum += sv[m]; }
        const float inv = 1.f / sum;
        u32 wpk[16];
#pragma unroll
        for (int m = 0; m < MM; m++) {
            const float wv = sv[m] * inv;
            const int hm = h * 32 + m;
            const size_t row = (size_t)(b * 256 + hm);
            sw_out[row * NN + gn] = wv;
            const u16 wb = f2bf(wv);
            wN[row * NN + gn] = wb;
            smem[hm * 256 + (((n_ >> 2) ^ (hm & 63)) << 2) + (n_ & 3)] = wb;
            if (m & 1) wpk[m >> 1] |= ((u32)wb << 16); else wpk[m >> 1] = (u32)wb;
        }
        u16* wrow = wT + ((size_t)(b * NN) + gn) * 256 + h * 32;
#pragma unroll
        for (int p = 0; p < 4; p++) {
            uint4 q4; q4.x = wpk[4 * p]; q4.y = wpk[4 * p + 1]; q4.z = wpk[4 * p + 2]; q4.w = wpk[4 * p + 3];
            *(uint4*)&wrow[p * 8] = q4;
        }
    }
    __syncthreads();

    // ---- pnorm: thread t -> hm = t>>1, half = t&1 (128 n each)
    {
        const int hm2 = t >> 1, half = t & 1;
        float s = 0.f;
        for (int j = 0; j < 128; j++) {
            const int n2 = half * 128 + j;
            s += bf2f(smem[hm2 * 256 + (((n2 >> 2) ^ (hm2 & 63)) << 2) + (n2 & 3)]);
        }
        s += __shfl_xor(s, 1);
        if (half == 0)
            pnorm[((size_t)(b * 8 + (hm2 >> 5)) * 64 + g) * MM + (hm2 & 31)] = s;
    }
}

// ---------------------------------------------------------------- unified 8-phase GEMM (256x256), MODE 2 bf16 C
template<int MODE>
__global__ __launch_bounds__(512, 1) void gemm_nt(
        const u16* __restrict__ A, const u16* __restrict__ Bm,
        const float* __restrict__ bias, void* __restrict__ Cout,
        int NCols, int Kd, int ldk, int ntn, int bofs, int bshift,
        long long bstrideB, long long kCstride) {
    __shared__ u16 ldsA[2][2][8192];
    __shared__ u16 ldsB[2][2][8192];
    const int t = threadIdx.x, l = t & 63, w = t >> 6;
    const int wr = w >> 2, wc = w & 3;

    const int nwg = gridDim.x, cpx = nwg >> 3, bid = blockIdx.x;
    const int swz = (nwg >= 8) ? ((bid & 7) * cpx + (bid >> 3)) : bid;
    const int tm = swz / ntn, tn = swz % ntn;
    const int ks = blockIdx.y;
    const u16* Bb = Bm + (size_t)(tm >> bshift) * bstrideB;

    f32x4 acc[8][4];
    const f32x4 zero = {0.f, 0.f, 0.f, 0.f};
#pragma unroll
    for (int mi = 0; mi < 8; mi++)
#pragma unroll
        for (int ni = 0; ni < 4; ni++) acc[mi][ni] = zero;

    const int srow = w * 8 + (l >> 3);
    const int skel = ((l & 7) ^ ((l >> 3) & 7)) * 8;
    const u16* gA = A  + (size_t)(tm * 256 + srow) * ldk + (size_t)ks * Kd + skel;
    const u16* gB = Bb + (size_t)(tn * 256 + srow) * ldk + (size_t)ks * Kd + skel;
    const int ldo = w * 512 + l * 8;

#define STAGE_A(T, H) { const u16* g_ = gA + (size_t)((H) * 128) * ldk + (T) * 64; \
    u16* d_ = &ldsA[(T) & 1][H][ldo]; gload16(g_, d_); gload16(g_ + (size_t)64 * ldk, d_ + 4096); }
#define STAGE_B(T, H) { const u16* g_ = gB + (size_t)((H) * 128) * ldk + (T) * 64; \
    u16* d_ = &ldsB[(T) & 1][H][ldo]; gload16(g_, d_); gload16(g_ + (size_t)64 * ldk, d_ + 4096); }

    const int m16 = l & 15;
    const int ck0 = (((l >> 4) + 0) ^ (l & 7)) << 3;
    const int ck1 = (((l >> 4) + 4) ^ (l & 7)) << 3;
    const int brb = (wc & 1) * 64;
    const int nT = Kd >> 6;

    STAGE_A(0, 0); STAGE_A(0, 1); STAGE_B(0, 0); STAGE_B(0, 1);
    STAGE_B(1, 0); STAGE_B(1, 1);
    asm volatile("s_waitcnt vmcnt(4)" ::: "memory");
    __builtin_amdgcn_s_barrier();

    for (int kt = 0; kt < nT; ++kt) {
        const int sl = kt & 1;
        const u16* lA = ldsA[sl][wr];
        const u16* lB = ldsB[sl][wc >> 1];
        short8 aF[4][2], bF[4][2];

#pragma unroll
        for (int fr = 0; fr < 4; fr++) {
            aF[fr][0] = *(const short8*)&lA[(fr * 16 + m16) * 64 + ck0];
            aF[fr][1] = *(const short8*)&lA[(fr * 16 + m16) * 64 + ck1];
        }
#pragma unroll
        for (int fc = 0; fc < 2; fc++) {
            bF[fc][0] = *(const short8*)&lB[(brb + fc * 16 + m16) * 64 + ck0];
            bF[fc][1] = *(const short8*)&lB[(brb + fc * 16 + m16) * 64 + ck1];
        }
        if (kt + 1 < nT) STAGE_A(kt + 1, 0);
        __builtin_amdgcn_s_barrier();
        asm volatile("s_waitcnt lgkmcnt(0)" ::: "memory");
        __builtin_amdgcn_s_setprio(1);
#pragma unroll
        for (int kk = 0; kk < 2; kk++)
#pragma unroll
            for (int mi = 0; mi < 4; mi++) {
                acc[mi][0] = MFMA16(aF[mi][kk], bF[0][kk], acc[mi][0]);
                acc[mi][1] = MFMA16(aF[mi][kk], bF[1][kk], acc[mi][1]);
            }
        __builtin_amdgcn_s_setprio(0);
        __builtin_amdgcn_s_barrier();

#pragma unroll
        for (int fc = 2; fc < 4; fc++) {
            bF[fc][0] = *(const short8*)&lB[(brb + fc * 16 + m16) * 64 + ck0];
            bF[fc][1] = *(const short8*)&lB[(brb + fc * 16 + m16) * 64 + ck1];
        }
        if (kt + 1 < nT) STAGE_A(kt + 1, 1);
        __builtin_amdgcn_s_barrier();
        asm volatile("s_waitcnt lgkmcnt(0)" ::: "memory");
        __builtin_amdgcn_s_setprio(1);
#pragma unroll
        for (int kk = 0; kk < 2; kk++)
#pragma unroll
            for (int mi = 0; mi < 4; mi++) {
                acc[mi][2] = MFMA16(aF[mi][kk], bF[2][kk], acc[mi][2]);
                acc[mi][3] = MFMA16(aF[mi][kk], bF[3][kk], acc[mi][3]);
            }
        __builtin_amdgcn_s_setprio(0);
        __builtin_amdgcn_s_barrier();

#pragma unroll
        for (int fr = 0; fr < 4; fr++) {
            aF[fr][0] = *(const short8*)&lA[((fr + 4) * 16 + m16) * 64 + ck0];
            aF[fr][1] = *(const short8*)&lA[((fr + 4) * 16 + m16) * 64 + ck1];
        }
        if (kt + 2 < nT) STAGE_B(kt + 2, 0);
        __builtin_amdgcn_s_barrier();
        asm volatile("s_waitcnt lgkmcnt(0)" ::: "memory");
        __builtin_amdgcn_s_setprio(1);
#pragma unroll
        for (int kk = 0; kk < 2; kk++)
#pragma unroll
            for (int mi = 0; mi < 4; mi++) {
                acc[4 + mi][0] = MFMA16(aF[mi][kk], bF[0][kk], acc[4 + mi][0]);
                acc[4 + mi][1] = MFMA16(aF[mi][kk], bF[1][kk], acc[4 + mi][1]);
            }
        __builtin_amdgcn_s_setprio(0);
        __builtin_amdgcn_s_barrier();

        if (kt + 2 < nT) STAGE_B(kt + 2, 1);
        __builtin_amdgcn_s_barrier();
        __builtin_amdgcn_s_setprio(1);
#pragma unroll
        for (int kk = 0; kk < 2; kk++)
#pragma unroll
            for (int mi = 0; mi < 4; mi++) {
                acc[4 + mi][2] = MFMA16(aF[mi][kk], bF[2][kk], acc[4 + mi][2]);
                acc[4 + mi][3] = MFMA16(aF[mi][kk], bF[3][kk], acc[4 + mi][3]);
            }
        __builtin_amdgcn_s_setprio(0);
        if (kt < nT - 1) {
            if (kt + 2 < nT) asm volatile("s_waitcnt vmcnt(4)" ::: "memory");
            else             asm volatile("s_waitcnt vmcnt(0)" ::: "memory");
            __builtin_amdgcn_s_barrier();
        }
    }
#undef STAGE_A
#undef STAGE_B

    const int cr = (l >> 4) * 4;
    const int cc = l & 15;
    if (MODE == 2) {
        u16* Cp = (u16*)Cout + (size_t)ks * kCstride;
#pragma unroll
        for (int ni = 0; ni < 4; ni++) {
            const int col = tn * 256 + wc * 64 + ni * 16 + cc;
            const float bv = bias ? bias[col] : 0.0f;
#pragma unroll
            for (int mi = 0; mi < 8; mi++) {
                const int row0 = tm * 256 + wr * 128 + mi * 16 + cr;
#pragma unroll
                for (int q = 0; q < 4; q++)
                    Cp[(size_t)(row0 + q) * NCols + col] = f2bf(acc[mi][ni][q] + bv);
            }
        }
    } else {
        float* Cp = (float*)Cout + (size_t)ks * kCstride;
#pragma unroll
        for (int ni = 0; ni < 4; ni++) {
            const int col = tn * 256 + wc * 64 + ni * 16 + cc;
            const float bv = bias ? bias[col] : 0.0f;
#pragma unroll
            for (int mi = 0; mi < 8; mi++) {
                const int row0 = tm * 256 + wr * 128 + mi * 16 + cr;
#pragma unroll
                for (int q = 0; q < 4; q++)
                    Cp[(size_t)(row0 + q) * NCols + col] = acc[mi][ni][q] + bv;
            }
        }
    }
}

// ---------------------------------------------------------------- small 2-phase GEMM (128x128, BK=32, 16 KB LDS)
// __launch_bounds__(256, 4): ~4 blocks/CU so finished blocks' C-writes overlap
// resident neighbors' staging (write-bound gemm3).
__global__ __launch_bounds__(256, 4) void gemm_small(
        const u16* __restrict__ A, const u16* __restrict__ Bm,
        const float* __restrict__ bias, float* __restrict__ Cout,
        int Ncols, int Kds, int ldk, int ntn, int bshift,
        long long bstrideB, long long kCstride) {
    __shared__ u16 lds_a[128 * 32];
    __shared__ u16 lds_b[128 * 32];
    const int t = threadIdx.x, l = t & 63, w = t >> 6;
    const int wr = w >> 1, wc = w & 1;

    const int nwg = gridDim.x, cpx = nwg >> 3, bid = blockIdx.x;
    const int swz = (nwg >= 8) ? ((bid & 7) * cpx + (bid >> 3)) : bid;
    const int tm = swz / ntn, tn = swz % ntn;
    const int ks = blockIdx.y;
    const u16* Bb = Bm + (size_t)(tm >> bshift) * bstrideB;

    f32x4 acc[4][4];
    const f32x4 zero = {0.f, 0.f, 0.f, 0.f};
#pragma unroll
    for (int mi = 0; mi < 4; mi++)
#pragma unroll
        for (int ni = 0; ni < 4; ni++) acc[mi][ni] = zero;

    const int srow = w * 32 + (l >> 2);
    const int scol = (l & 3) * 8;
    const u16* ga = A  + (size_t)(tm * 128 + srow) * ldk + (size_t)ks * Kds + scol;
    const u16* gb = Bb + (size_t)(tn * 128 + srow) * ldk + (size_t)ks * Kds + scol;
    u16* la = &lds_a[(w * 32) * 32];
    u16* lb = &lds_b[(w * 32) * 32];
    const size_t rstep = (size_t)16 * ldk;

    const int nK = Kds >> 5;
    const int kg = (l >> 4) * 8;
    const int ra = wr * 64 + (l & 15);
    const int rb = wc * 64 + (l & 15);

    for (int kt = 0; kt < nK; kt++) {
        __syncthreads();
        const int ko = kt << 5;
        gload16(ga + ko,         la);
        gload16(ga + ko + rstep, la + 16 * 32);
        gload16(gb + ko,         lb);
        gload16(gb + ko + rstep, lb + 16 * 32);
        __syncthreads();

        short8 af[4], bfr[4];
#pragma unroll
        for (int mi = 0; mi < 4; mi++) af[mi] = *(const short8*)&lds_a[(ra + mi * 16) * 32 + kg];
#pragma unroll
        for (int ni = 0; ni < 4; ni++) bfr[ni] = *(const short8*)&lds_b[(rb + ni * 16) * 32 + kg];
#pragma unroll
        for (int mi = 0; mi < 4; mi++)
#pragma unroll
            for (int ni = 0; ni < 4; ni++)
                acc[mi][ni] = MFMA16(af[mi], bfr[ni], acc[mi][ni]);
    }

    float* Cp = Cout + (size_t)ks * kCstride;
#pragma unroll
    for (int ni = 0; ni < 4; ni++) {
        const int col = tn * 128 + wc * 64 + ni * 16 + (l & 15);
        const float bv = bias ? bias[col] : 0.0f;
#pragma unroll
        for (int mi = 0; mi < 4; mi++) {
            const int row0 = tm * 128 + wr * 64 + mi * 16 + ((l >> 4) << 2);
#pragma unroll
            for (int q = 0; q < 4; q++)
                Cp[(size_t)(row0 + q) * Ncols + col] = acc[mi][ni][q] + bv;
        }
    }
}

// ---------------------------------------------------------------- sum U k-split bf16 partials (16) -> reordered bf16 U2
__global__ __launch_bounds__(256) void sum_U(const u16* __restrict__ U_part, u16* __restrict__ U2) {
    const int i = blockIdx.x * 256 + threadIdx.x;   // 262144 groups of 4 elems
    float4 s = make_float4(0.f, 0.f, 0.f, 0.f);
    for (int ks = 0; ks < 16; ks++) {
        const ushort4 v = ((const ushort4*)(U_part + (size_t)ks * 1048576))[i];
        s.x += bf2f(v.x); s.y += bf2f(v.y); s.z += bf2f(v.z); s.w += bf2f(v.w);
    }
    const int r = i >> 8, e4 = i & 255;
    const int b = r >> 8, h = (r >> 5) & 7, m = r & 31;
    const int r2 = h * 128 + b * 32 + m;
    ushort4 o; o.x = f2bf(s.x); o.y = f2bf(s.y); o.z = f2bf(s.z); o.w = f2bf(s.w);
    ((ushort4*)U2)[r2 * 256 + e4] = o;
}

// ---------------------------------------------------------------- st_fix: st_red = (sum_ks C2 + bv*norm)/(norm+eps), bf16
__global__ __launch_bounds__(256) void st_fix(const float* __restrict__ C2,
                                              const float* __restrict__ pnorm,
                                              const float* __restrict__ bkv,
                                              u16* __restrict__ st_red) {
    __shared__ float norm[MM];
    const int bh = blockIdx.x, b = bh >> 3, h = bh & 7, t = threadIdx.x;
    if (t < MM) {
        float s = 0.f;
        for (int g = 0; g < 64; g++) s += pnorm[((size_t)bh * 64 + g) * MM + t];
        norm[t] = s;
    }
    __syncthreads();
#pragma unroll
    for (int i = 0; i < 16; i++) {
        const int idx = t * 16 + i;
        const int m = idx >> 7, d = idx & 127;
        const float nv = norm[m];
        float c = 0.f;
        const size_t off = (size_t)(h * 128 + d) * 128 + b * 32 + m;
#pragma unroll
        for (int ks = 0; ks < 8; ks++) c += C2[(size_t)ks * 131072 + off];
        const float v = (c + bkv[1024 + h * 128 + d] * nv) / (nv + 1e-5f);
        st_red[(size_t)bh * 4096 + idx] = f2bf(v);
    }
}

// ---------------------------------------------------------------- qt_kernel
__global__ __launch_bounds__(256) void qt_kernel(const u16* __restrict__ st_red,
                                                 const float* __restrict__ qkvp,
                                                 float* __restrict__ qt_g) {
    __shared__ u16 st_lds[MM * DD];
    const int es = blockIdx.x, bh = blockIdx.y, h = bh & 7, t = threadIdx.x;
    {
        const uint4* src = (const uint4*)(st_red + (size_t)bh * 4096);
        ((uint4*)st_lds)[t] = src[t];
        ((uint4*)st_lds)[t + 256] = src[t + 256];
    }
    __syncthreads();
    const float* qw = qkvp + (size_t)h * DD * 384;
#pragma unroll
    for (int i = 0; i < 4; i++) {
        const int idx = t + i * 256;
        const int m = idx >> 5, el = idx & 31;
        const int e = es * 32 + el;
        float s = 0.f;
        for (int d = 0; d < DD; d++) s += bf2f(st_lds[m * DD + d]) * qw[d * 384 + e];
        qt_g[((size_t)bh * MM + m) * 384 + e] = s;
    }
}

// ---------------------------------------------------------------- finalize2 (per b,h)
__global__ void finalize2_kernel(const float* __restrict__ qt_g,
                                 float* __restrict__ attn_out, float* __restrict__ otw) {
    __shared__ float qt[MM * 384];
    __shared__ float dots[MM * MM];
    const int bh = blockIdx.x, t = threadIdx.x;

#pragma unroll
    for (int i = 0; i < 12; i++)
        ((float4*)qt)[t + i * 256] = ((const float4*)(qt_g + (size_t)bh * 12288))[t + i * 256];
    __syncthreads();
    const float scale = 0.08838834764831845f;
#pragma unroll
    for (int i = 0; i < 4; i++) {
        int idx = t * 4 + i;
        int qi = idx >> 5, kj = idx & 31;
        float s = 0.f;
        for (int d = 0; d < DD; d++) s += qt[qi * 384 + d] * qt[kj * 384 + 128 + d];
        dots[idx] = s * scale;
    }
    __syncthreads();
    if (t < MM) {
        float mx = -1e30f;
        float ex[MM];
#pragma unroll
        for (int j = 0; j < MM; j++) mx = fmaxf(mx, dots[t * MM + j]);
        float sm = 0.f;
#pragma unroll
        for (int j = 0; j < MM; j++) { ex[j] = __expf(dots[t * MM + j] - mx); sm += ex[j]; }
        float inv = 1.f / sm;
#pragma unroll
        for (int j = 0; j < MM; j++) {
            float v = ex[j] * inv;
            dots[t * MM + j] = v;
            attn_out[((size_t)bh * MM + t) * MM + j] = v;
        }
    }
    __syncthreads();
#pragma unroll
    for (int i = 0; i < 16; i++) {
        int e = t + i * 256;
        int m = e >> 7, d = e & 127;
        float s = 0.f;
#pragma unroll
        for (int j = 0; j < MM; j++) s += dots[m * MM + j] * qt[j * 384 + 256 + d];
        otw[(size_t)bh * 4096 + e] = s;
    }
}

// ---------------------------------------------------------------- zmat
__global__ __launch_bounds__(256) void zmat_kernel(const float* __restrict__ otw,
                                                   const float* __restrict__ outw,
                                                   u16* __restrict__ Zt) {
    __shared__ float ot_lds[MM * DD];
    const int bh = blockIdx.y, b = bh >> 3, h = bh & 7;
    const int es = blockIdx.x;
    const int t = threadIdx.x;
    for (int i = t; i < MM * DD; i += 256) ot_lds[i] = otw[(size_t)bh * 4096 + i];
    __syncthreads();
    const int e = es * 128 + (t >> 1);
    const int m0 = (t & 1) * 16;
    const float* ow = outw + (size_t)e * HDIM + h * DD;
    float acc[16];
#pragma unroll
    for (int m = 0; m < 16; m++) acc[m] = 0.f;
    for (int d = 0; d < DD; d += 4) {
        float4 o4 = *(const float4*)&ow[d];
#pragma unroll
        for (int m = 0; m < 16; m++) {
            const float* otr = &ot_lds[(m0 + m) * DD + d];
            acc[m] += o4.x * otr[0] + o4.y * otr[1] + o4.z * otr[2] + o4.w * otr[3];
        }
    }
    u32 pk[8];
#pragma unroll
    for (int p = 0; p < 8; p++)
        pk[p] = (u32)f2bf(acc[2 * p]) | ((u32)f2bf(acc[2 * p + 1]) << 16);
    u16* dst = Zt + ((size_t)b * 1024 + e) * 256 + h * MM + m0;
#pragma unroll
    for (int p = 0; p < 2; p++) {
        uint4 q4; q4.x = pk[4 * p]; q4.y = pk[4 * p + 1]; q4.z = pk[4 * p + 2]; q4.w = pk[4 * p + 3];
        *(uint4*)&dst[p * 8] = q4;
    }
}

// ---------------------------------------------------------------- launch
extern "C" void kernel_launch(void* const* d_in, const int* in_sizes, int n_in,
                              void* d_out, int out_size, void* d_ws, size_t ws_size,
                              hipStream_t stream) {
    const float* x        = (const float*)d_in[0];
    const float* wkv      = (const float*)d_in[1];
    const float* bkv      = (const float*)d_in[2];
    const float* wtq      = (const float*)d_in[3];
    const float* wtq_bias = (const float*)d_in[4];
    const float* qkvp     = (const float*)d_in[5];
    const float* outw     = (const float*)d_in[6];
    const float* outb     = (const float*)d_in[7];

    float* out  = (float*)d_out;
    float* out0 = out;                      // [B,N,HD]
    float* out1 = out + 67108864;           // slice_weights
    float* out2 = out + 83886080;           // temperature + bias
    float* out4 = out + 83886337;           // attn_weights

    char* ws = (char*)d_ws;
    u16*   xb     = (u16*)(ws);                         // 134 MB
    u16*   xbT    = (u16*)(ws + 134217728);             // 134 MB [b][e][n]
    u16*   wN     = (u16*)(ws + 268435456);             // 33.5 MB [b*256+hm][n]
    u16*   wT     = (u16*)(ws + 301989888);             // 33.5 MB [b*16384+n][256 hm]
    u16*   U_part = (u16*)(ws + 335544320);             // 33.5 MB (16 x 1024x1024 bf16)
    u16*   U2     = (u16*)(ws + 402653184);             // 2 MB [h*128+b*32+m][1024 e]
    float* C2     = (float*)(ws + 404750336);           // 4 MB (8 x 1024x128 f32)
    u16*   wvb    = (u16*)(ws + 409468928);             // 2 MB
    u16*   WQb    = (u16*)(ws + 411566080);             // 512 KB
    float* wqbias = (float*)(ws + 412090368);           // 1 KB
    float* pnorm  = (float*)(ws + 412091392);           // 256 KB
    u16*   st_red = (u16*)(ws + 412353536);             // 256 KB
    float* otws   = (float*)(ws + 412615680);           // 512 KB
    u16*   Zt     = (u16*)(ws + 413138944);             // 2 MB
    float* qt_g   = (float*)(ws + 415236096);           // 1.5 MB

    convert_kernel<<<dim3(4096), dim3(256), 0, stream>>>(x, xb, xbT, wtq_bias, out2);
    wq_kernel<<<dim3(8, 8), dim3(256), 0, stream>>>(wtq, wkv, bkv, WQb, wqbias, wvb);
    // fused: scores GEMM + softmax + weight outputs
    gemm_score_sm<<<dim3(256), dim3(512), 0, stream>>>(xb, WQb, wqbias, out1, wN, wT, pnorm);
    // U = w @ x : 8-phase, split-K x16 over n (Kd=1024 each), bf16 partials
    gemm_nt<2><<<dim3(16, 16), dim3(512), 0, stream>>>(wN, xbT, nullptr, (void*)U_part,
                                                       1024, 1024, 16384, 4, 0, 0,
                                                       (long long)16777216, (long long)1048576);
    sum_U<<<dim3(1024), dim3(256), 0, stream>>>(U_part, U2);
    // C2[ks][hd][b*32+m] = Wv_h @ U2_h^T, per-h diagonal tiles, split-K x8
    gemm_small<<<dim3(8, 8), dim3(256), 0, stream>>>(wvb, U2, nullptr, C2,
                                                     128, 128, 1024, 1, 0,
                                                     (long long)131072, (long long)131072);
    st_fix<<<dim3(32), dim3(256), 0, stream>>>(C2, pnorm, bkv, st_red);
    qt_kernel<<<dim3(12, 32), dim3(256), 0, stream>>>(st_red, qkvp, qt_g);
    finalize2_kernel<<<dim3(32), dim3(256), 0, stream>>>(qt_g, out4, otws);
    zmat_kernel<<<dim3(8, 32), dim3(256), 0, stream>>>(otws, outw, Zt);
    // out0 = wT @ Zt^T (+outb), 128^2 tiles
    gemm_small<<<dim3(4096), dim3(256), 0, stream>>>(wT, Zt, outb, out0,
                                                     1024, 256, 256, 8, 7,
                                                     (long long)262144, 0);
}